// Round 8
// baseline (141.899 us; speedup 1.0000x reference)
//
#include <hip/hip_runtime.h>
#include <cstddef>

// B=8192 trees, 16 leaves + 1 root. FEAT=480 (14 tok x 16 emb + 256 lstm).
// prep_kernel: read-coalesced bf16 transposes (lc/nf W1/W2, hi/lo cs/cb), emb,
//              endvec, vfin/cfin collapse of the final linear chain.
// mlp1_mfma:   fused gather + MFMA MLP (480->128 relu ->32 relu), 64 rows/block,
//              ONE row-tile per wave (halved per-wave gather), direct L2 W1T
//              reads (no K-loop barriers), hoisted token loads, packed stores.
// scan_mfma:   32 trees/block x 256 blocks x 4 waves (R6-verbatim), hi/lo split
//              MFMA, weights register-resident, fused final dot.

typedef __bf16 bf16x8 __attribute__((ext_vector_type(8)));
typedef __bf16 bf16x4 __attribute__((ext_vector_type(4)));
typedef float  f32x4  __attribute__((ext_vector_type(4)));

__global__ __launch_bounds__(256) void prep_kernel(
    const float* __restrict__ embedding,
    const float* __restrict__ leaf_end_W, const float* __restrict__ leaf_end_b,
    const float* __restrict__ lc_W1, const float* __restrict__ lc_W2,
    const float* __restrict__ nf_W1, const float* __restrict__ nf_W2,
    const float* __restrict__ cs_W1, const float* __restrict__ cs_W2,
    const float* __restrict__ cb_W1, const float* __restrict__ cb_W2,
    const float* __restrict__ ff_W1, const float* __restrict__ ff_b1,
    const float* __restrict__ ff_W2, const float* __restrict__ ff_b2,
    const float* __restrict__ ts_W, const float* __restrict__ ts_b,
    __bf16* __restrict__ lcW1T, __bf16* __restrict__ nfW1T,
    __bf16* __restrict__ lcW2T, __bf16* __restrict__ nfW2T,
    __bf16* __restrict__ emb_bf, float* __restrict__ endvec,
    __bf16* __restrict__ csW1Th, __bf16* __restrict__ csW1Tl,
    __bf16* __restrict__ cbW1Th, __bf16* __restrict__ cbW1Tl,
    __bf16* __restrict__ csW2Th, __bf16* __restrict__ csW2Tl,
    __bf16* __restrict__ cbW2Th, __bf16* __restrict__ cbW2Tl,
    float* __restrict__ vfin, float* __restrict__ cfin)
{
    const int id = blockIdx.x * 256 + threadIdx.x;
    if (id < 61440) {                        // lc_W1[k][n] read coalesced
        const int k = id >> 7, n = id & 127;
        lcW1T[n * 480 + k] = (__bf16)lc_W1[id];
    } else if (id < 122880) {
        const int e = id - 61440;
        const int k = e >> 7, n = e & 127;
        nfW1T[n * 480 + k] = (__bf16)nf_W1[e];
    } else if (id < 126976) {                // lc_W2[k][n] read coalesced
        const int e = id - 122880;
        const int k = e >> 5, n = e & 31;
        lcW2T[n * 128 + k] = (__bf16)lc_W2[e];
    } else if (id < 131072) {
        const int e = id - 126976;
        const int k = e >> 5, n = e & 31;
        nfW2T[n * 128 + k] = (__bf16)nf_W2[e];
    } else if (id < 134272) {
        emb_bf[id - 131072] = (__bf16)embedding[id - 131072];
    } else if (id < 134304) {                // endvec = emb[1] @ leaf_end_W + b
        const int c = id - 134272;
        float a = leaf_end_b[c];
        #pragma unroll
        for (int d = 0; d < 16; ++d) a = fmaf(embedding[16 + d], leaf_end_W[d * 32 + c], a);
        endvec[c] = a;
    } else if (id < 142496) {                // cs_W1 hi/lo  [64][128] -> T[128][64]
        const int e = id - 134304;
        const int k = e >> 7, n = e & 127;
        const float v = cs_W1[e];
        const __bf16 h = (__bf16)v;
        csW1Th[n * 64 + k] = h; csW1Tl[n * 64 + k] = (__bf16)(v - (float)h);
    } else if (id < 150688) {                // cb_W1 hi/lo
        const int e = id - 142496;
        const int k = e >> 7, n = e & 127;
        const float v = cb_W1[e];
        const __bf16 h = (__bf16)v;
        cbW1Th[n * 64 + k] = h; cbW1Tl[n * 64 + k] = (__bf16)(v - (float)h);
    } else if (id < 154784) {                // cs_W2 hi/lo  [128][32] -> T[32][128]
        const int e = id - 150688;
        const int k = e >> 5, n = e & 31;
        const float v = cs_W2[e];
        const __bf16 h = (__bf16)v;
        csW2Th[n * 128 + k] = h; csW2Tl[n * 128 + k] = (__bf16)(v - (float)h);
    } else if (id < 158880) {                // cb_W2 hi/lo
        const int e = id - 154784;
        const int k = e >> 5, n = e & 31;
        const float v = cb_W2[e];
        const __bf16 h = (__bf16)v;
        cbW2Th[n * 128 + k] = h; cbW2Tl[n * 128 + k] = (__bf16)(v - (float)h);
    } else if (id < 158912) {                // vfin[c] = ff_W1[c] . (ff_W2 @ ts_W)
        const int c = id - 158880;
        float w2t[32];
        #pragma unroll
        for (int k = 0; k < 32; ++k) {
            float a = 0.f;
            for (int j = 0; j < 32; ++j) a = fmaf(ff_W2[k * 32 + j], ts_W[j], a);
            w2t[k] = a;
        }
        float a = 0.f;
        #pragma unroll
        for (int k = 0; k < 32; ++k) a = fmaf(ff_W1[c * 32 + k], w2t[k], a);
        vfin[c] = a;
    } else if (id == 158912) {
        float a = ts_b[0];
        for (int j = 0; j < 32; ++j) a = fmaf(ff_b2[j], ts_W[j], a);
        for (int k = 0; k < 32; ++k) {
            float w2t = 0.f;
            for (int j = 0; j < 32; ++j) w2t = fmaf(ff_W2[k * 32 + j], ts_W[j], w2t);
            a = fmaf(ff_b1[k], w2t, a);
        }
        cfin[0] = a;
    }
}

// 64 rows/block: leaf blocks 0..2047 (131072 leaf rows), node blocks 2048..2175.
// Wave w owns rows w*16..w*16+15 (one tile) x all 128 W1-cols (8 N-tiles).
__global__ __launch_bounds__(256, 4) void mlp1_mfma(
    const int* __restrict__ trees,
    const float* __restrict__ lstm,
    const __bf16* __restrict__ lcW1T, const __bf16* __restrict__ nfW1T,
    const __bf16* __restrict__ lcW2T, const __bf16* __restrict__ nfW2T,
    const __bf16* __restrict__ emb_bf, const float* __restrict__ endvec,
    const float* __restrict__ lc_b1, const float* __restrict__ lc_b2,
    const float* __restrict__ nf_b1, const float* __restrict__ nf_b2,
    __bf16* __restrict__ childrenH, __bf16* __restrict__ childrenL,
    __bf16* __restrict__ node_tmpH, __bf16* __restrict__ node_tmpL)
{
    __shared__ __align__(16) __bf16 emb_s[200 * 24];   // padded stride 24 (48B)
    __shared__ __align__(16) __bf16 Hs[64][136];
    __shared__ float b1s[128], b2s[32], evs[32];
    __shared__ int   endf[64];

    const int tid = threadIdx.x;
    const int blk = blockIdx.x;
    const bool leaf = (blk < 2048);

    const __bf16* __restrict__ W1T = leaf ? lcW1T : nfW1T;
    const __bf16* __restrict__ W2T = leaf ? lcW2T : nfW2T;
    const float*  __restrict__ b1p = leaf ? lc_b1 : nf_b1;
    const float*  __restrict__ b2p = leaf ? lc_b2 : nf_b2;

    const int l  = tid & 63;
    const int w  = tid >> 6;        // wave 0..3
    const int lm = l & 15;
    const int kb = l >> 4;          // k sub-block 0..3

    // this lane's gather row: row = w*16 + lm (kb-quads share the row)
    const int row = w * 16 + lm;
    int b, trow;
    if (leaf) { const int R = blk * 64 + row; b = R >> 4; trow = 1 + (R & 15); }
    else      { b = (blk - 2048) * 64 + row; trow = 0; }
    const int* __restrict__ ti = trees + (b * 17 + trow) * 17;

    // hoisted token + pointer loads (independent, issue before the barrier)
    int tk[14];
    #pragma unroll
    for (int j = 0; j < 14; ++j) tk[j] = ti[2 + j];
    const int ptr = ti[16];
    const float* __restrict__ lrow = lstm + ((size_t)b * 64 + (size_t)ptr) * 256;

    // staging (padded embedding rows)
    for (int i = tid; i < 3200; i += 256) {
        const int r = i >> 4, c = i & 15;
        emb_s[r * 24 + c] = emb_bf[i];
    }
    if (tid < 128) b1s[tid] = b1p[tid];
    if (tid < 32)  { b2s[tid] = b2p[tid]; evs[tid] = leaf ? endvec[tid] : 0.f; }
    if (tid < 64) {
        if (leaf) {
            const int R = blk * 64 + tid;
            const int bb = R >> 4, tr = 1 + (R & 15);
            endf[tid] = (trees[(bb * 17 + tr) * 17 + 2] == 1);
        } else endf[tid] = 0;
    }

    f32x4 acc[8];
    #pragma unroll
    for (int j = 0; j < 8; ++j) acc[j] = (f32x4){0.f, 0.f, 0.f, 0.f};

    __syncthreads();

    // layer 1: 480 -> 128 in 15 K-chunks of 32. A = W1 cols (L2), B = this tile's rows.
    #pragma unroll
    for (int c = 0; c < 15; ++c) {
        bf16x8 bfr;
        if (c < 7) {
            const int tok = (kb >> 1) ? tk[2 * c + 1] : tk[2 * c];
            bfr = *(const bf16x8*)(emb_s + tok * 24 + (kb & 1) * 8);
        } else {
            const float* p = lrow + (c - 7) * 32 + kb * 8;
            const float4 u = *(const float4*)p;
            const float4 v = *(const float4*)(p + 4);
            bf16x8 t;
            t[0] = (__bf16)u.x; t[1] = (__bf16)u.y; t[2] = (__bf16)u.z; t[3] = (__bf16)u.w;
            t[4] = (__bf16)v.x; t[5] = (__bf16)v.y; t[6] = (__bf16)v.z; t[7] = (__bf16)v.w;
            bfr = t;
        }
        #pragma unroll
        for (int ct = 0; ct < 8; ++ct) {
            const bf16x8 wfr = *(const bf16x8*)(W1T + (ct * 16 + lm) * 480 + c * 32 + kb * 8);
            acc[ct] = __builtin_amdgcn_mfma_f32_16x16x32_bf16(wfr, bfr, acc[ct], 0, 0, 0);
        }
    }

    // D: col(lane&15) = row-in-tile, row(4*kb+rg) = W1-col -> packed 4-col store
    #pragma unroll
    for (int ct = 0; ct < 8; ++ct) {
        const int wcol = ct * 16 + 4 * kb;
        bf16x4 pk;
        #pragma unroll
        for (int rg = 0; rg < 4; ++rg) {
            float v = acc[ct][rg] + b1s[wcol + rg];
            v = v > 0.f ? v : 0.f;
            pk[rg] = (__bf16)v;
        }
        *(bf16x4*)&Hs[w * 16 + lm][wcol] = pk;
    }
    __syncthreads();

    // layer 2: 64x32. wave w: outcol tile jn=w&1, row-tiles {2*(w>>1)+i}.
    const int jn = w & 1, rb2 = 2 * (w >> 1);
    f32x4 acc2[2];
    acc2[0] = (f32x4){0.f, 0.f, 0.f, 0.f};
    acc2[1] = (f32x4){0.f, 0.f, 0.f, 0.f};

    #pragma unroll
    for (int kc = 0; kc < 4; ++kc) {
        const bf16x8 wf = *(const bf16x8*)(W2T + (jn * 16 + lm) * 128 + kc * 32 + kb * 8);
        #pragma unroll
        for (int i = 0; i < 2; ++i) {
            const bf16x8 hf = *(const bf16x8*)(&Hs[(rb2 + i) * 16 + lm][kc * 32 + kb * 8]);
            acc2[i] = __builtin_amdgcn_mfma_f32_16x16x32_bf16(wf, hf, acc2[i], 0, 0, 0);
        }
    }

    #pragma unroll
    for (int i = 0; i < 2; ++i) {
        const int orow = (rb2 + i) * 16 + lm;     // row within block
        const int ocol = jn * 16 + 4 * kb;        // +rg
        const bool isend = leaf && endf[orow];
        bf16x4 ph, pl;
        #pragma unroll
        for (int rg = 0; rg < 4; ++rg) {
            float v = acc2[i][rg] + b2s[ocol + rg];
            v = v > 0.f ? v : 0.f;
            if (isend) v = evs[ocol + rg];
            const __bf16 h = (__bf16)v;
            ph[rg] = h;
            pl[rg] = (__bf16)(v - (float)h);
        }
        if (leaf) {
            const size_t R = (size_t)blk * 64 + orow;
            *(bf16x4*)&childrenH[R * 32 + ocol] = ph;
            *(bf16x4*)&childrenL[R * 32 + ocol] = pl;
        } else {
            const size_t R = (size_t)(blk - 2048) * 64 + orow;
            *(bf16x4*)&node_tmpH[R * 32 + ocol] = ph;
            *(bf16x4*)&node_tmpL[R * 32 + ocol] = pl;
        }
    }
}

// 32 trees/block, 256 blocks, 4 waves (R6-verbatim). Swapped operands; packed LDS IO.
__global__ __launch_bounds__(256) void scan_mfma(
    const __bf16* __restrict__ childrenH, const __bf16* __restrict__ childrenL,
    const __bf16* __restrict__ node_tmpH, const __bf16* __restrict__ node_tmpL,
    const __bf16* __restrict__ csW1Th, const __bf16* __restrict__ csW1Tl,
    const __bf16* __restrict__ csW2Th, const __bf16* __restrict__ csW2Tl,
    const __bf16* __restrict__ cbW1Th, const __bf16* __restrict__ cbW1Tl,
    const __bf16* __restrict__ cbW2Th, const __bf16* __restrict__ cbW2Tl,
    const float* __restrict__ cs_b1, const float* __restrict__ cs_b2,
    const float* __restrict__ cb_b1, const float* __restrict__ cb_b2,
    const float* __restrict__ vfin_g, const float* __restrict__ cfin_g,
    float* __restrict__ out)
{
    __shared__ __align__(16) __bf16 Xh[32][72], Xl[32][72];
    __shared__ __align__(16) __bf16 Hh[32][136], Hl[32][136];
    __shared__ float b1a[128], b1b[128], b2a[32], b2b[32], vfin[32];
    __shared__ float psum[2][32];
    __shared__ float cfin_s;

    const int tid = threadIdx.x;
    const int l = tid & 63, w = tid >> 6;      // 4 waves
    const int lm = l & 15, kb = l >> 4;

    if (tid < 128)      { b1a[tid] = cs_b1[tid]; b1b[tid] = cb_b1[tid]; }
    else if (tid < 160) { b2a[tid - 128] = cs_b2[tid - 128]; b2b[tid - 128] = cb_b2[tid - 128]; }
    else if (tid < 192) { vfin[tid - 160] = vfin_g[tid - 160]; }
    else if (tid == 192) cfin_s = cfin_g[0];

    // layer1 weights (A-frags): wave w owns cols [w*32, +32): 2 tiles x 2 K-chunks
    bf16x8 W1r[2][2][2];   // [nt][kc][hi/lo]
    #pragma unroll
    for (int nt = 0; nt < 2; ++nt)
        #pragma unroll
        for (int kc = 0; kc < 2; ++kc) {
            const int n = w * 32 + nt * 16 + lm;
            W1r[nt][kc][0] = *(const bf16x8*)(csW1Th + n * 64 + kc * 32 + kb * 8);
            W1r[nt][kc][1] = *(const bf16x8*)(csW1Tl + n * 64 + kc * 32 + kb * 8);
        }
    // layer2 weights: wave w owns outcols (w&1)*16.. ; 4 K-chunks
    bf16x8 W2r[4][2];
    {
        const int n2 = (w & 1) * 16 + lm;
        #pragma unroll
        for (int kc = 0; kc < 4; ++kc) {
            W2r[kc][0] = *(const bf16x8*)(csW2Th + n2 * 128 + kc * 32 + kb * 8);
            W2r[kc][1] = *(const bf16x8*)(csW2Tl + n2 * 128 + kc * 32 + kb * 8);
        }
    }

    const size_t base = (size_t)blockIdx.x * 32;
    const int tt = tid >> 3, c4 = (tid & 7) * 4;    // staging: tree tt, cols c4..

    {
        const size_t o0 = ((base + tt) * 16 + 0) * 32 + c4;
        const size_t o1 = ((base + tt) * 16 + 1) * 32 + c4;
        *(bf16x4*)&Xh[tt][c4]      = *(const bf16x4*)(childrenH + o0);
        *(bf16x4*)&Xl[tt][c4]      = *(const bf16x4*)(childrenL + o0);
        *(bf16x4*)&Xh[tt][32 + c4] = *(const bf16x4*)(childrenH + o1);
        *(bf16x4*)&Xl[tt][32 + c4] = *(const bf16x4*)(childrenL + o1);
    }
    __syncthreads();

    #pragma unroll 1
    for (int it = 1; it <= 16; ++it) {
        const bool fin = (it == 16);
        if (fin) {   // swap to cb weights (last iteration)
            #pragma unroll
            for (int nt = 0; nt < 2; ++nt)
                #pragma unroll
                for (int kc = 0; kc < 2; ++kc) {
                    const int n = w * 32 + nt * 16 + lm;
                    W1r[nt][kc][0] = *(const bf16x8*)(cbW1Th + n * 64 + kc * 32 + kb * 8);
                    W1r[nt][kc][1] = *(const bf16x8*)(cbW1Tl + n * 64 + kc * 32 + kb * 8);
                }
            const int n2 = (w & 1) * 16 + lm;
            #pragma unroll
            for (int kc = 0; kc < 4; ++kc) {
                W2r[kc][0] = *(const bf16x8*)(cbW2Th + n2 * 128 + kc * 32 + kb * 8);
                W2r[kc][1] = *(const bf16x8*)(cbW2Tl + n2 * 128 + kc * 32 + kb * 8);
            }
        }
        const float* __restrict__ b1c = fin ? b1b : b1a;
        const float* __restrict__ b2c = fin ? b2b : b2a;

        // prefetch next child (or node_tmp before the combine step)
        bf16x4 pfh, pfl;
        const int pfmode = (it < 15) ? 1 : (it == 15 ? 2 : 0);
        if (pfmode == 1) {
            const size_t o = ((base + tt) * 16 + (it + 1)) * 32 + c4;
            pfh = *(const bf16x4*)(childrenH + o);
            pfl = *(const bf16x4*)(childrenL + o);
        } else if (pfmode == 2) {
            const size_t o = (base + tt) * 32 + c4;
            pfh = *(const bf16x4*)(node_tmpH + o);
            pfl = *(const bf16x4*)(node_tmpL + o);
        }

        // ---- layer 1: A=W1 (cols), B=X (trees) ----
        bf16x8 xh[2][2], xl[2][2];
        #pragma unroll
        for (int tn = 0; tn < 2; ++tn)
            #pragma unroll
            for (int kc = 0; kc < 2; ++kc) {
                xh[tn][kc] = *(const bf16x8*)&Xh[tn * 16 + lm][kc * 32 + kb * 8];
                xl[tn][kc] = *(const bf16x8*)&Xl[tn * 16 + lm][kc * 32 + kb * 8];
            }
        f32x4 a1[2][2];
        #pragma unroll
        for (int tn = 0; tn < 2; ++tn)
            #pragma unroll
            for (int nt = 0; nt < 2; ++nt) {
                a1[tn][nt] = (f32x4){0.f, 0.f, 0.f, 0.f};
                #pragma unroll
                for (int kc = 0; kc < 2; ++kc) {
                    a1[tn][nt] = __builtin_amdgcn_mfma_f32_16x16x32_bf16(W1r[nt][kc][0], xh[tn][kc], a1[tn][nt], 0, 0, 0);
                    a1[tn][nt] = __builtin_amdgcn_mfma_f32_16x16x32_bf16(W1r[nt][kc][0], xl[tn][kc], a1[tn][nt], 0, 0, 0);
                    a1[tn][nt] = __builtin_amdgcn_mfma_f32_16x16x32_bf16(W1r[nt][kc][1], xh[tn][kc], a1[tn][nt], 0, 0, 0);
                }
            }
        // D: col = tree-in-tile, row = W1-col -> packed stores
        #pragma unroll
        for (int tn = 0; tn < 2; ++tn)
            #pragma unroll
            for (int nt = 0; nt < 2; ++nt) {
                const int wcol = w * 32 + nt * 16 + 4 * kb;
                bf16x4 ph, pl;
                #pragma unroll
                for (int rg = 0; rg < 4; ++rg) {
                    float v = a1[tn][nt][rg] + b1c[wcol + rg];
                    v = v > 0.f ? v : 0.f;
                    const __bf16 h = (__bf16)v;
                    ph[rg] = h;
                    pl[rg] = (__bf16)(v - (float)h);
                }
                *(bf16x4*)&Hh[tn * 16 + lm][wcol] = ph;
                *(bf16x4*)&Hl[tn * 16 + lm][wcol] = pl;
            }
        __syncthreads();

        // ---- layer 2: A=W2, B=H ----
        const int mt = w >> 1, jn = w & 1;
        f32x4 a2 = (f32x4){0.f, 0.f, 0.f, 0.f};
        #pragma unroll
        for (int kc = 0; kc < 4; ++kc) {
            const bf16x8 hh = *(const bf16x8*)&Hh[mt * 16 + lm][kc * 32 + kb * 8];
            const bf16x8 hl = *(const bf16x8*)&Hl[mt * 16 + lm][kc * 32 + kb * 8];
            a2 = __builtin_amdgcn_mfma_f32_16x16x32_bf16(W2r[kc][0], hh, a2, 0, 0, 0);
            a2 = __builtin_amdgcn_mfma_f32_16x16x32_bf16(W2r[kc][0], hl, a2, 0, 0, 0);
            a2 = __builtin_amdgcn_mfma_f32_16x16x32_bf16(W2r[kc][1], hh, a2, 0, 0, 0);
        }

        if (!fin) {
            // new carry: tree = mt*16+lm, feats jn*16+4kb..+3 (packed)
            const int cb_ = (it == 15) ? 32 : 0;
            const int ocol = jn * 16 + 4 * kb;
            bf16x4 ph, pl;
            #pragma unroll
            for (int rg = 0; rg < 4; ++rg) {
                float v = a2[rg] + b2c[ocol + rg];
                v = v > 0.f ? v : 0.f;
                const __bf16 h = (__bf16)v;
                ph[rg] = h;
                pl[rg] = (__bf16)(v - (float)h);
            }
            *(bf16x4*)&Xh[mt * 16 + lm][cb_ + ocol] = ph;
            *(bf16x4*)&Xl[mt * 16 + lm][cb_ + ocol] = pl;
            if (pfmode) {
                const int dst = (pfmode == 2) ? 0 : 32;
                *(bf16x4*)&Xh[tt][dst + c4] = pfh;
                *(bf16x4*)&Xl[tt][dst + c4] = pfl;
            }
            __syncthreads();
        } else {
            // fused final linear: out = tree_sum . vfin + cfin
            const int ocol = jn * 16 + 4 * kb;
            float p = 0.f;
            #pragma unroll
            for (int rg = 0; rg < 4; ++rg) {
                float v = a2[rg] + b2c[ocol + rg];
                v = v > 0.f ? v : 0.f;
                p = fmaf(v, vfin[ocol + rg], p);
            }
            p += __shfl_xor(p, 16, 64);
            p += __shfl_xor(p, 32, 64);
            if (kb == 0) psum[jn][mt * 16 + lm] = p;
            __syncthreads();
            if (tid < 32) out[base + tid] = cfin_s + psum[0][tid] + psum[1][tid];
        }
    }
}

extern "C" void kernel_launch(void* const* d_in, const int* in_sizes, int n_in,
                              void* d_out, int out_size, void* d_ws, size_t ws_size,
                              hipStream_t stream) {
    const int*   trees      = (const int*)d_in[0];
    const float* lstm       = (const float*)d_in[1];
    const float* embedding  = (const float*)d_in[4];
    const float* leaf_end_W = (const float*)d_in[5];
    const float* leaf_end_b = (const float*)d_in[6];
    const float* lc_W1 = (const float*)d_in[7];
    const float* lc_b1 = (const float*)d_in[8];
    const float* lc_W2 = (const float*)d_in[9];
    const float* lc_b2 = (const float*)d_in[10];
    const float* cs_W1 = (const float*)d_in[11];
    const float* cs_b1 = (const float*)d_in[12];
    const float* cs_W2 = (const float*)d_in[13];
    const float* cs_b2 = (const float*)d_in[14];
    const float* nf_W1 = (const float*)d_in[15];
    const float* nf_b1 = (const float*)d_in[16];
    const float* nf_W2 = (const float*)d_in[17];
    const float* nf_b2 = (const float*)d_in[18];
    const float* cb_W1 = (const float*)d_in[19];
    const float* cb_b1 = (const float*)d_in[20];
    const float* cb_W2 = (const float*)d_in[21];
    const float* cb_b2 = (const float*)d_in[22];
    const float* ff_W1 = (const float*)d_in[23];
    const float* ff_b1 = (const float*)d_in[24];
    const float* ff_W2 = (const float*)d_in[25];
    const float* ff_b2 = (const float*)d_in[26];
    const float* ts_W  = (const float*)d_in[27];
    const float* ts_b  = (const float*)d_in[28];

    char* ws = (char*)d_ws;
    __bf16* childrenH = (__bf16*)ws;                             // 8 MiB
    __bf16* childrenL = (__bf16*)(ws + 8388608);                 // 8 MiB
    __bf16* node_tmpH = (__bf16*)(ws + 16777216);                // 0.5 MiB
    __bf16* node_tmpL = (__bf16*)(ws + 17301504);                // 0.5 MiB
    __bf16* lcW1T    = (__bf16*)(ws + 17825792);
    __bf16* nfW1T    = (__bf16*)(ws + 17948672);
    __bf16* lcW2T    = (__bf16*)(ws + 18071552);
    __bf16* nfW2T    = (__bf16*)(ws + 18079744);
    __bf16* emb_bf   = (__bf16*)(ws + 18087936);
    float*  endvec   = (float*)(ws + 18094336);
    __bf16* csW1Th   = (__bf16*)(ws + 18094464);
    __bf16* csW1Tl   = (__bf16*)(ws + 18110848);
    __bf16* cbW1Th   = (__bf16*)(ws + 18127232);
    __bf16* cbW1Tl   = (__bf16*)(ws + 18143616);
    __bf16* csW2Th   = (__bf16*)(ws + 18160000);
    __bf16* csW2Tl   = (__bf16*)(ws + 18168192);
    __bf16* cbW2Th   = (__bf16*)(ws + 18176384);
    __bf16* cbW2Tl   = (__bf16*)(ws + 18184576);
    float*  vfin     = (float*)(ws + 18192768);
    float*  cfin     = (float*)(ws + 18192896);
    float*  outp     = (float*)d_out;

    prep_kernel<<<dim3(621), dim3(256), 0, stream>>>(
        embedding, leaf_end_W, leaf_end_b, lc_W1, lc_W2, nf_W1, nf_W2,
        cs_W1, cs_W2, cb_W1, cb_W2, ff_W1, ff_b1, ff_W2, ff_b2, ts_W, ts_b,
        lcW1T, nfW1T, lcW2T, nfW2T, emb_bf, endvec,
        csW1Th, csW1Tl, cbW1Th, cbW1Tl, csW2Th, csW2Tl, cbW2Th, cbW2Tl,
        vfin, cfin);

    mlp1_mfma<<<dim3(2176), dim3(256), 0, stream>>>(
        trees, lstm, lcW1T, nfW1T, lcW2T, nfW2T, emb_bf, endvec,
        lc_b1, lc_b2, nf_b1, nf_b2, childrenH, childrenL, node_tmpH, node_tmpL);

    scan_mfma<<<dim3(256), dim3(256), 0, stream>>>(
        childrenH, childrenL, node_tmpH, node_tmpL,
        csW1Th, csW1Tl, csW2Th, csW2Tl, cbW1Th, cbW1Tl, cbW2Th, cbW2Tl,
        cs_b1, cs_b2, cb_b1, cb_b2, vfin, cfin, outp);
}

// Round 9
// 133.091 us; speedup vs baseline: 1.0662x; 1.0662x over previous
//
#include <hip/hip_runtime.h>
#include <cstddef>

// B=8192 trees, 16 leaves + 1 root. FEAT=480 (14 tok x 16 emb + 256 lstm).
// prep_kernel: read-coalesced bf16 transposes (lc/nf W1/W2, hi/lo cs/cb), emb,
//              endvec, vfin/cfin collapse of the final linear chain.
// mlp1_mfma:   R6 structure (64 rows/block, 2 row-tiles x 1 col-half per wave,
//              barrier-free K-loop, packed stores, padded emb LDS) + lstm
//              B-fragments PRELOADED to bf16 registers before the barrier so
//              the K-loop's only memory op is the W1T L2 stream.
// scan_mfma:   32 trees/block x 256 blocks x 4 waves (R6-verbatim), hi/lo split
//              MFMA, weights register-resident, fused final dot.

typedef __bf16 bf16x8 __attribute__((ext_vector_type(8)));
typedef __bf16 bf16x4 __attribute__((ext_vector_type(4)));
typedef float  f32x4  __attribute__((ext_vector_type(4)));

__global__ __launch_bounds__(256) void prep_kernel(
    const float* __restrict__ embedding,
    const float* __restrict__ leaf_end_W, const float* __restrict__ leaf_end_b,
    const float* __restrict__ lc_W1, const float* __restrict__ lc_W2,
    const float* __restrict__ nf_W1, const float* __restrict__ nf_W2,
    const float* __restrict__ cs_W1, const float* __restrict__ cs_W2,
    const float* __restrict__ cb_W1, const float* __restrict__ cb_W2,
    const float* __restrict__ ff_W1, const float* __restrict__ ff_b1,
    const float* __restrict__ ff_W2, const float* __restrict__ ff_b2,
    const float* __restrict__ ts_W, const float* __restrict__ ts_b,
    __bf16* __restrict__ lcW1T, __bf16* __restrict__ nfW1T,
    __bf16* __restrict__ lcW2T, __bf16* __restrict__ nfW2T,
    __bf16* __restrict__ emb_bf, float* __restrict__ endvec,
    __bf16* __restrict__ csW1Th, __bf16* __restrict__ csW1Tl,
    __bf16* __restrict__ cbW1Th, __bf16* __restrict__ cbW1Tl,
    __bf16* __restrict__ csW2Th, __bf16* __restrict__ csW2Tl,
    __bf16* __restrict__ cbW2Th, __bf16* __restrict__ cbW2Tl,
    float* __restrict__ vfin, float* __restrict__ cfin)
{
    const int id = blockIdx.x * 256 + threadIdx.x;
    if (id < 61440) {                        // lc_W1[k][n] read coalesced
        const int k = id >> 7, n = id & 127;
        lcW1T[n * 480 + k] = (__bf16)lc_W1[id];
    } else if (id < 122880) {
        const int e = id - 61440;
        const int k = e >> 7, n = e & 127;
        nfW1T[n * 480 + k] = (__bf16)nf_W1[e];
    } else if (id < 126976) {                // lc_W2[k][n] read coalesced
        const int e = id - 122880;
        const int k = e >> 5, n = e & 31;
        lcW2T[n * 128 + k] = (__bf16)lc_W2[e];
    } else if (id < 131072) {
        const int e = id - 126976;
        const int k = e >> 5, n = e & 31;
        nfW2T[n * 128 + k] = (__bf16)nf_W2[e];
    } else if (id < 134272) {
        emb_bf[id - 131072] = (__bf16)embedding[id - 131072];
    } else if (id < 134304) {                // endvec = emb[1] @ leaf_end_W + b
        const int c = id - 134272;
        float a = leaf_end_b[c];
        #pragma unroll
        for (int d = 0; d < 16; ++d) a = fmaf(embedding[16 + d], leaf_end_W[d * 32 + c], a);
        endvec[c] = a;
    } else if (id < 142496) {                // cs_W1 hi/lo  [64][128] -> T[128][64]
        const int e = id - 134304;
        const int k = e >> 7, n = e & 127;
        const float v = cs_W1[e];
        const __bf16 h = (__bf16)v;
        csW1Th[n * 64 + k] = h; csW1Tl[n * 64 + k] = (__bf16)(v - (float)h);
    } else if (id < 150688) {                // cb_W1 hi/lo
        const int e = id - 142496;
        const int k = e >> 7, n = e & 127;
        const float v = cb_W1[e];
        const __bf16 h = (__bf16)v;
        cbW1Th[n * 64 + k] = h; cbW1Tl[n * 64 + k] = (__bf16)(v - (float)h);
    } else if (id < 154784) {                // cs_W2 hi/lo  [128][32] -> T[32][128]
        const int e = id - 150688;
        const int k = e >> 5, n = e & 31;
        const float v = cs_W2[e];
        const __bf16 h = (__bf16)v;
        csW2Th[n * 128 + k] = h; csW2Tl[n * 128 + k] = (__bf16)(v - (float)h);
    } else if (id < 158880) {                // cb_W2 hi/lo
        const int e = id - 154784;
        const int k = e >> 5, n = e & 31;
        const float v = cb_W2[e];
        const __bf16 h = (__bf16)v;
        cbW2Th[n * 128 + k] = h; cbW2Tl[n * 128 + k] = (__bf16)(v - (float)h);
    } else if (id < 158912) {                // vfin[c] = ff_W1[c] . (ff_W2 @ ts_W)
        const int c = id - 158880;
        float w2t[32];
        #pragma unroll
        for (int k = 0; k < 32; ++k) {
            float a = 0.f;
            for (int j = 0; j < 32; ++j) a = fmaf(ff_W2[k * 32 + j], ts_W[j], a);
            w2t[k] = a;
        }
        float a = 0.f;
        #pragma unroll
        for (int k = 0; k < 32; ++k) a = fmaf(ff_W1[c * 32 + k], w2t[k], a);
        vfin[c] = a;
    } else if (id == 158912) {
        float a = ts_b[0];
        for (int j = 0; j < 32; ++j) a = fmaf(ff_b2[j], ts_W[j], a);
        for (int k = 0; k < 32; ++k) {
            float w2t = 0.f;
            for (int j = 0; j < 32; ++j) w2t = fmaf(ff_W2[k * 32 + j], ts_W[j], w2t);
            a = fmaf(ff_b1[k], w2t, a);
        }
        cfin[0] = a;
    }
}

// 64 rows/block: leaf blocks 0..2047 (131072 leaf rows), node blocks 2048..2175.
// Swapped operands: A = weights (m = out-col), B = gathered rows (n = row).
__global__ __launch_bounds__(256, 4) void mlp1_mfma(
    const int* __restrict__ trees,
    const float* __restrict__ lstm,
    const __bf16* __restrict__ lcW1T, const __bf16* __restrict__ nfW1T,
    const __bf16* __restrict__ lcW2T, const __bf16* __restrict__ nfW2T,
    const __bf16* __restrict__ emb_bf, const float* __restrict__ endvec,
    const float* __restrict__ lc_b1, const float* __restrict__ lc_b2,
    const float* __restrict__ nf_b1, const float* __restrict__ nf_b2,
    __bf16* __restrict__ childrenH, __bf16* __restrict__ childrenL,
    __bf16* __restrict__ node_tmpH, __bf16* __restrict__ node_tmpL)
{
    __shared__ __align__(16) __bf16 emb_s[200 * 24];   // padded stride 24 (48B)
    __shared__ __align__(16) __bf16 Hs[64][136];
    __shared__ float b1s[128], b2s[32], evs[32];
    __shared__ int   endf[64];

    const int tid = threadIdx.x;
    const int blk = blockIdx.x;
    const bool leaf = (blk < 2048);

    const __bf16* __restrict__ W1T = leaf ? lcW1T : nfW1T;
    const __bf16* __restrict__ W2T = leaf ? lcW2T : nfW2T;
    const float*  __restrict__ b1p = leaf ? lc_b1 : nf_b1;
    const float*  __restrict__ b2p = leaf ? lc_b2 : nf_b2;

    const int l  = tid & 63;
    const int w  = tid >> 6;        // wave 0..3
    const int lm = l & 15;
    const int kb = l >> 4;          // k sub-block 0..3
    const int wm = w >> 1;          // row half (rows wm*32..+31)
    const int wn = w & 1;           // W1-col half (cols wn*64..+63)

    // gather pointers for this wave's 2 row-tiles
    const int* tb[2];
    const float* lb[2];
    #pragma unroll
    for (int i = 0; i < 2; ++i) {
        const int r = wm * 32 + i * 16 + lm;
        int b, trow;
        if (leaf) { const int R = blk * 64 + r; b = R >> 4; trow = 1 + (R & 15); }
        else      { b = (blk - 2048) * 64 + r; trow = 0; }
        const int* t = trees + (b * 17 + trow) * 17;
        tb[i] = t;
        lb[i] = lstm + ((size_t)b * 64 + (size_t)t[16]) * 256;
    }

    // PRELOAD all lstm B-fragments to bf16 registers (HBM latency hides under
    // the staging phase + barrier below). 16 x bf16x8 = 64 VGPR held.
    bf16x8 Bl[2][8];
    #pragma unroll
    for (int c = 0; c < 8; ++c)
        #pragma unroll
        for (int i = 0; i < 2; ++i) {
            const float* p = lb[i] + c * 32 + kb * 8;
            const float4 u = *(const float4*)p;
            const float4 v = *(const float4*)(p + 4);
            bf16x8 t;
            t[0] = (__bf16)u.x; t[1] = (__bf16)u.y; t[2] = (__bf16)u.z; t[3] = (__bf16)u.w;
            t[4] = (__bf16)v.x; t[5] = (__bf16)v.y; t[6] = (__bf16)v.z; t[7] = (__bf16)v.w;
            Bl[i][c] = t;
        }

    // staging (padded embedding rows)
    for (int i = tid; i < 3200; i += 256) {
        const int r = i >> 4, c = i & 15;
        emb_s[r * 24 + c] = emb_bf[i];
    }
    if (tid < 128) b1s[tid] = b1p[tid];
    if (tid < 32)  { b2s[tid] = b2p[tid]; evs[tid] = leaf ? endvec[tid] : 0.f; }
    if (tid < 64) {
        if (leaf) {
            const int R = blk * 64 + tid;
            const int bb = R >> 4, tr = 1 + (R & 15);
            endf[tid] = (trees[(bb * 17 + tr) * 17 + 2] == 1);
        } else endf[tid] = 0;
    }

    f32x4 acc[2][4];
    #pragma unroll
    for (int i = 0; i < 2; ++i)
        #pragma unroll
        for (int j = 0; j < 4; ++j) acc[i][j] = (f32x4){0.f, 0.f, 0.f, 0.f};

    __syncthreads();

    // layer 1, phase A: lstm K-chunks (B in registers; only W1T touches memory)
    #pragma unroll
    for (int c = 0; c < 8; ++c) {
        bf16x8 wfr[4];
        #pragma unroll
        for (int ct = 0; ct < 4; ++ct) {
            const int n = wn * 64 + ct * 16 + lm;
            wfr[ct] = *(const bf16x8*)(W1T + n * 480 + (7 + c) * 32 + kb * 8);
        }
        #pragma unroll
        for (int i = 0; i < 2; ++i)
            #pragma unroll
            for (int ct = 0; ct < 4; ++ct)
                acc[i][ct] = __builtin_amdgcn_mfma_f32_16x16x32_bf16(wfr[ct], Bl[i][c], acc[i][ct], 0, 0, 0);
    }

    // layer 1, phase B: embedding K-chunks (B from padded LDS)
    #pragma unroll
    for (int c = 0; c < 7; ++c) {
        bf16x8 wfr[4];
        #pragma unroll
        for (int ct = 0; ct < 4; ++ct) {
            const int n = wn * 64 + ct * 16 + lm;
            wfr[ct] = *(const bf16x8*)(W1T + n * 480 + c * 32 + kb * 8);
        }
        bf16x8 bfr[2];
        #pragma unroll
        for (int i = 0; i < 2; ++i) {
            const int tok = tb[i][2 + 2 * c + (kb >> 1)];
            bfr[i] = *(const bf16x8*)(emb_s + tok * 24 + (kb & 1) * 8);
        }
        #pragma unroll
        for (int i = 0; i < 2; ++i)
            #pragma unroll
            for (int ct = 0; ct < 4; ++ct)
                acc[i][ct] = __builtin_amdgcn_mfma_f32_16x16x32_bf16(wfr[ct], bfr[i], acc[i][ct], 0, 0, 0);
    }

    // D: col(lane&15) = row-in-tile, row(4*kb+rg) = W1-col -> packed 4-col store
    #pragma unroll
    for (int i = 0; i < 2; ++i)
        #pragma unroll
        for (int ct = 0; ct < 4; ++ct) {
            const int wcol = wn * 64 + ct * 16 + 4 * kb;
            bf16x4 pk;
            #pragma unroll
            for (int rg = 0; rg < 4; ++rg) {
                float v = acc[i][ct][rg] + b1s[wcol + rg];
                v = v > 0.f ? v : 0.f;
                pk[rg] = (__bf16)v;
            }
            *(bf16x4*)&Hs[wm * 32 + i * 16 + lm][wcol] = pk;
        }
    __syncthreads();

    // layer 2: 64x32. wave w: outcol tile jn=w&1, row-tiles {2*(w>>1)+i}.
    const int jn = w & 1, rb2 = 2 * (w >> 1);
    f32x4 acc2[2];
    acc2[0] = (f32x4){0.f, 0.f, 0.f, 0.f};
    acc2[1] = (f32x4){0.f, 0.f, 0.f, 0.f};

    #pragma unroll
    for (int kc = 0; kc < 4; ++kc) {
        const bf16x8 wf = *(const bf16x8*)(W2T + (jn * 16 + lm) * 128 + kc * 32 + kb * 8);
        #pragma unroll
        for (int i = 0; i < 2; ++i) {
            const bf16x8 hf = *(const bf16x8*)(&Hs[(rb2 + i) * 16 + lm][kc * 32 + kb * 8]);
            acc2[i] = __builtin_amdgcn_mfma_f32_16x16x32_bf16(wf, hf, acc2[i], 0, 0, 0);
        }
    }

    #pragma unroll
    for (int i = 0; i < 2; ++i) {
        const int orow = (rb2 + i) * 16 + lm;     // row within block
        const int ocol = jn * 16 + 4 * kb;        // +rg
        const bool isend = leaf && endf[orow];
        bf16x4 ph, pl;
        #pragma unroll
        for (int rg = 0; rg < 4; ++rg) {
            float v = acc2[i][rg] + b2s[ocol + rg];
            v = v > 0.f ? v : 0.f;
            if (isend) v = evs[ocol + rg];
            const __bf16 h = (__bf16)v;
            ph[rg] = h;
            pl[rg] = (__bf16)(v - (float)h);
        }
        if (leaf) {
            const size_t R = (size_t)blk * 64 + orow;
            *(bf16x4*)&childrenH[R * 32 + ocol] = ph;
            *(bf16x4*)&childrenL[R * 32 + ocol] = pl;
        } else {
            const size_t R = (size_t)(blk - 2048) * 64 + orow;
            *(bf16x4*)&node_tmpH[R * 32 + ocol] = ph;
            *(bf16x4*)&node_tmpL[R * 32 + ocol] = pl;
        }
    }
}

// 32 trees/block, 256 blocks, 4 waves (R6-verbatim). Swapped operands; packed LDS IO.
__global__ __launch_bounds__(256) void scan_mfma(
    const __bf16* __restrict__ childrenH, const __bf16* __restrict__ childrenL,
    const __bf16* __restrict__ node_tmpH, const __bf16* __restrict__ node_tmpL,
    const __bf16* __restrict__ csW1Th, const __bf16* __restrict__ csW1Tl,
    const __bf16* __restrict__ csW2Th, const __bf16* __restrict__ csW2Tl,
    const __bf16* __restrict__ cbW1Th, const __bf16* __restrict__ cbW1Tl,
    const __bf16* __restrict__ cbW2Th, const __bf16* __restrict__ cbW2Tl,
    const float* __restrict__ cs_b1, const float* __restrict__ cs_b2,
    const float* __restrict__ cb_b1, const float* __restrict__ cb_b2,
    const float* __restrict__ vfin_g, const float* __restrict__ cfin_g,
    float* __restrict__ out)
{
    __shared__ __align__(16) __bf16 Xh[32][72], Xl[32][72];
    __shared__ __align__(16) __bf16 Hh[32][136], Hl[32][136];
    __shared__ float b1a[128], b1b[128], b2a[32], b2b[32], vfin[32];
    __shared__ float psum[2][32];
    __shared__ float cfin_s;

    const int tid = threadIdx.x;
    const int l = tid & 63, w = tid >> 6;      // 4 waves
    const int lm = l & 15, kb = l >> 4;

    if (tid < 128)      { b1a[tid] = cs_b1[tid]; b1b[tid] = cb_b1[tid]; }
    else if (tid < 160) { b2a[tid - 128] = cs_b2[tid - 128]; b2b[tid - 128] = cb_b2[tid - 128]; }
    else if (tid < 192) { vfin[tid - 160] = vfin_g[tid - 160]; }
    else if (tid == 192) cfin_s = cfin_g[0];

    // layer1 weights (A-frags): wave w owns cols [w*32, +32): 2 tiles x 2 K-chunks
    bf16x8 W1r[2][2][2];   // [nt][kc][hi/lo]
    #pragma unroll
    for (int nt = 0; nt < 2; ++nt)
        #pragma unroll
        for (int kc = 0; kc < 2; ++kc) {
            const int n = w * 32 + nt * 16 + lm;
            W1r[nt][kc][0] = *(const bf16x8*)(csW1Th + n * 64 + kc * 32 + kb * 8);
            W1r[nt][kc][1] = *(const bf16x8*)(csW1Tl + n * 64 + kc * 32 + kb * 8);
        }
    // layer2 weights: wave w owns outcols (w&1)*16.. ; 4 K-chunks
    bf16x8 W2r[4][2];
    {
        const int n2 = (w & 1) * 16 + lm;
        #pragma unroll
        for (int kc = 0; kc < 4; ++kc) {
            W2r[kc][0] = *(const bf16x8*)(csW2Th + n2 * 128 + kc * 32 + kb * 8);
            W2r[kc][1] = *(const bf16x8*)(csW2Tl + n2 * 128 + kc * 32 + kb * 8);
        }
    }

    const size_t base = (size_t)blockIdx.x * 32;
    const int tt = tid >> 3, c4 = (tid & 7) * 4;    // staging: tree tt, cols c4..

    {
        const size_t o0 = ((base + tt) * 16 + 0) * 32 + c4;
        const size_t o1 = ((base + tt) * 16 + 1) * 32 + c4;
        *(bf16x4*)&Xh[tt][c4]      = *(const bf16x4*)(childrenH + o0);
        *(bf16x4*)&Xl[tt][c4]      = *(const bf16x4*)(childrenL + o0);
        *(bf16x4*)&Xh[tt][32 + c4] = *(const bf16x4*)(childrenH + o1);
        *(bf16x4*)&Xl[tt][32 + c4] = *(const bf16x4*)(childrenL + o1);
    }
    __syncthreads();

    #pragma unroll 1
    for (int it = 1; it <= 16; ++it) {
        const bool fin = (it == 16);
        if (fin) {   // swap to cb weights (last iteration)
            #pragma unroll
            for (int nt = 0; nt < 2; ++nt)
                #pragma unroll
                for (int kc = 0; kc < 2; ++kc) {
                    const int n = w * 32 + nt * 16 + lm;
                    W1r[nt][kc][0] = *(const bf16x8*)(cbW1Th + n * 64 + kc * 32 + kb * 8);
                    W1r[nt][kc][1] = *(const bf16x8*)(cbW1Tl + n * 64 + kc * 32 + kb * 8);
                }
            const int n2 = (w & 1) * 16 + lm;
            #pragma unroll
            for (int kc = 0; kc < 4; ++kc) {
                W2r[kc][0] = *(const bf16x8*)(cbW2Th + n2 * 128 + kc * 32 + kb * 8);
                W2r[kc][1] = *(const bf16x8*)(cbW2Tl + n2 * 128 + kc * 32 + kb * 8);
            }
        }
        const float* __restrict__ b1c = fin ? b1b : b1a;
        const float* __restrict__ b2c = fin ? b2b : b2a;

        // prefetch next child (or node_tmp before the combine step)
        bf16x4 pfh, pfl;
        const int pfmode = (it < 15) ? 1 : (it == 15 ? 2 : 0);
        if (pfmode == 1) {
            const size_t o = ((base + tt) * 16 + (it + 1)) * 32 + c4;
            pfh = *(const bf16x4*)(childrenH + o);
            pfl = *(const bf16x4*)(childrenL + o);
        } else if (pfmode == 2) {
            const size_t o = (base + tt) * 32 + c4;
            pfh = *(const bf16x4*)(node_tmpH + o);
            pfl = *(const bf16x4*)(node_tmpL + o);
        }

        // ---- layer 1: A=W1 (cols), B=X (trees) ----
        bf16x8 xh[2][2], xl[2][2];
        #pragma unroll
        for (int tn = 0; tn < 2; ++tn)
            #pragma unroll
            for (int kc = 0; kc < 2; ++kc) {
                xh[tn][kc] = *(const bf16x8*)&Xh[tn * 16 + lm][kc * 32 + kb * 8];
                xl[tn][kc] = *(const bf16x8*)&Xl[tn * 16 + lm][kc * 32 + kb * 8];
            }
        f32x4 a1[2][2];
        #pragma unroll
        for (int tn = 0; tn < 2; ++tn)
            #pragma unroll
            for (int nt = 0; nt < 2; ++nt) {
                a1[tn][nt] = (f32x4){0.f, 0.f, 0.f, 0.f};
                #pragma unroll
                for (int kc = 0; kc < 2; ++kc) {
                    a1[tn][nt] = __builtin_amdgcn_mfma_f32_16x16x32_bf16(W1r[nt][kc][0], xh[tn][kc], a1[tn][nt], 0, 0, 0);
                    a1[tn][nt] = __builtin_amdgcn_mfma_f32_16x16x32_bf16(W1r[nt][kc][0], xl[tn][kc], a1[tn][nt], 0, 0, 0);
                    a1[tn][nt] = __builtin_amdgcn_mfma_f32_16x16x32_bf16(W1r[nt][kc][1], xh[tn][kc], a1[tn][nt], 0, 0, 0);
                }
            }
        // D: col = tree-in-tile, row = W1-col -> packed stores
        #pragma unroll
        for (int tn = 0; tn < 2; ++tn)
            #pragma unroll
            for (int nt = 0; nt < 2; ++nt) {
                const int wcol = w * 32 + nt * 16 + 4 * kb;
                bf16x4 ph, pl;
                #pragma unroll
                for (int rg = 0; rg < 4; ++rg) {
                    float v = a1[tn][nt][rg] + b1c[wcol + rg];
                    v = v > 0.f ? v : 0.f;
                    const __bf16 h = (__bf16)v;
                    ph[rg] = h;
                    pl[rg] = (__bf16)(v - (float)h);
                }
                *(bf16x4*)&Hh[tn * 16 + lm][wcol] = ph;
                *(bf16x4*)&Hl[tn * 16 + lm][wcol] = pl;
            }
        __syncthreads();

        // ---- layer 2: A=W2, B=H ----
        const int mt = w >> 1, jn = w & 1;
        f32x4 a2 = (f32x4){0.f, 0.f, 0.f, 0.f};
        #pragma unroll
        for (int kc = 0; kc < 4; ++kc) {
            const bf16x8 hh = *(const bf16x8*)&Hh[mt * 16 + lm][kc * 32 + kb * 8];
            const bf16x8 hl = *(const bf16x8*)&Hl[mt * 16 + lm][kc * 32 + kb * 8];
            a2 = __builtin_amdgcn_mfma_f32_16x16x32_bf16(W2r[kc][0], hh, a2, 0, 0, 0);
            a2 = __builtin_amdgcn_mfma_f32_16x16x32_bf16(W2r[kc][0], hl, a2, 0, 0, 0);
            a2 = __builtin_amdgcn_mfma_f32_16x16x32_bf16(W2r[kc][1], hh, a2, 0, 0, 0);
        }

        if (!fin) {
            // new carry: tree = mt*16+lm, feats jn*16+4kb..+3 (packed)
            const int cb_ = (it == 15) ? 32 : 0;
            const int ocol = jn * 16 + 4 * kb;
            bf16x4 ph, pl;
            #pragma unroll
            for (int rg = 0; rg < 4; ++rg) {
                float v = a2[rg] + b2c[ocol + rg];
                v = v > 0.f ? v : 0.f;
                const __bf16 h = (__bf16)v;
                ph[rg] = h;
                pl[rg] = (__bf16)(v - (float)h);
            }
            *(bf16x4*)&Xh[mt * 16 + lm][cb_ + ocol] = ph;
            *(bf16x4*)&Xl[mt * 16 + lm][cb_ + ocol] = pl;
            if (pfmode) {
                const int dst = (pfmode == 2) ? 0 : 32;
                *(bf16x4*)&Xh[tt][dst + c4] = pfh;
                *(bf16x4*)&Xl[tt][dst + c4] = pfl;
            }
            __syncthreads();
        } else {
            // fused final linear: out = tree_sum . vfin + cfin
            const int ocol = jn * 16 + 4 * kb;
            float p = 0.f;
            #pragma unroll
            for (int rg = 0; rg < 4; ++rg) {
                float v = a2[rg] + b2c[ocol + rg];
                v = v > 0.f ? v : 0.f;
                p = fmaf(v, vfin[ocol + rg], p);
            }
            p += __shfl_xor(p, 16, 64);
            p += __shfl_xor(p, 32, 64);
            if (kb == 0) psum[jn][mt * 16 + lm] = p;
            __syncthreads();
            if (tid < 32) out[base + tid] = cfin_s + psum[0][tid] + psum[1][tid];
        }
    }
}

extern "C" void kernel_launch(void* const* d_in, const int* in_sizes, int n_in,
                              void* d_out, int out_size, void* d_ws, size_t ws_size,
                              hipStream_t stream) {
    const int*   trees      = (const int*)d_in[0];
    const float* lstm       = (const float*)d_in[1];
    const float* embedding  = (const float*)d_in[4];
    const float* leaf_end_W = (const float*)d_in[5];
    const float* leaf_end_b = (const float*)d_in[6];
    const float* lc_W1 = (const float*)d_in[7];
    const float* lc_b1 = (const float*)d_in[8];
    const float* lc_W2 = (const float*)d_in[9];
    const float* lc_b2 = (const float*)d_in[10];
    const float* cs_W1 = (const float*)d_in[11];
    const float* cs_b1 = (const float*)d_in[12];
    const float* cs_W2 = (const float*)d_in[13];
    const float* cs_b2 = (const float*)d_in[14];
    const float* nf_W1 = (const float*)d_in[15];
    const float* nf_b1 = (const float*)d_in[16];
    const float* nf_W2 = (const float*)d_in[17];
    const float* nf_b2 = (const float*)d_in[18];
    const float* cb_W1 = (const float*)d_in[19];
    const float* cb_b1 = (const float*)d_in[20];
    const float* cb_W2 = (const float*)d_in[21];
    const float* cb_b2 = (const float*)d_in[22];
    const float* ff_W1 = (const float*)d_in[23];
    const float* ff_b1 = (const float*)d_in[24];
    const float* ff_W2 = (const float*)d_in[25];
    const float* ff_b2 = (const float*)d_in[26];
    const float* ts_W  = (const float*)d_in[27];
    const float* ts_b  = (const float*)d_in[28];

    char* ws = (char*)d_ws;
    __bf16* childrenH = (__bf16*)ws;                             // 8 MiB
    __bf16* childrenL = (__bf16*)(ws + 8388608);                 // 8 MiB
    __bf16* node_tmpH = (__bf16*)(ws + 16777216);                // 0.5 MiB
    __bf16* node_tmpL = (__bf16*)(ws + 17301504);                // 0.5 MiB
    __bf16* lcW1T    = (__bf16*)(ws + 17825792);
    __bf16* nfW1T    = (__bf16*)(ws + 17948672);
    __bf16* lcW2T    = (__bf16*)(ws + 18071552);
    __bf16* nfW2T    = (__bf16*)(ws + 18079744);
    __bf16* emb_bf   = (__bf16*)(ws + 18087936);
    float*  endvec   = (float*)(ws + 18094336);
    __bf16* csW1Th   = (__bf16*)(ws + 18094464);
    __bf16* csW1Tl   = (__bf16*)(ws + 18110848);
    __bf16* cbW1Th   = (__bf16*)(ws + 18127232);
    __bf16* cbW1Tl   = (__bf16*)(ws + 18143616);
    __bf16* csW2Th   = (__bf16*)(ws + 18160000);
    __bf16* csW2Tl   = (__bf16*)(ws + 18168192);
    __bf16* cbW2Th   = (__bf16*)(ws + 18176384);
    __bf16* cbW2Tl   = (__bf16*)(ws + 18184576);
    float*  vfin     = (float*)(ws + 18192768);
    float*  cfin     = (float*)(ws + 18192896);
    float*  outp     = (float*)d_out;

    prep_kernel<<<dim3(621), dim3(256), 0, stream>>>(
        embedding, leaf_end_W, leaf_end_b, lc_W1, lc_W2, nf_W1, nf_W2,
        cs_W1, cs_W2, cb_W1, cb_W2, ff_W1, ff_b1, ff_W2, ff_b2, ts_W, ts_b,
        lcW1T, nfW1T, lcW2T, nfW2T, emb_bf, endvec,
        csW1Th, csW1Tl, cbW1Th, cbW1Tl, csW2Th, csW2Tl, cbW2Th, cbW2Tl,
        vfin, cfin);

    mlp1_mfma<<<dim3(2176), dim3(256), 0, stream>>>(
        trees, lstm, lcW1T, nfW1T, lcW2T, nfW2T, emb_bf, endvec,
        lc_b1, lc_b2, nf_b1, nf_b2, childrenH, childrenL, node_tmpH, node_tmpL);

    scan_mfma<<<dim3(256), dim3(256), 0, stream>>>(
        childrenH, childrenL, node_tmpH, node_tmpL,
        csW1Th, csW1Tl, csW2Th, csW2Tl, cbW1Th, cbW1Tl, cbW2Th, cbW2Tl,
        cs_b1, cs_b2, cb_b1, cb_b2, vfin, cfin, outp);
}

// Round 10
// 127.570 us; speedup vs baseline: 1.1123x; 1.0433x over previous
//
#include <hip/hip_runtime.h>
#include <cstddef>

// B=8192 trees, 16 leaves + 1 root. FEAT=480 (14 tok x 16 emb + 256 lstm).
// prep_kernel: read-coalesced bf16 transposes (lc/nf W1/W2, hi/lo cs/cb), emb,
//              endvec, vfin/cfin collapse of the final linear chain.
// mlp1_mfma:   R6-exact: 64 rows/block, 2 row-tiles x 1 col-half per wave,
//              barrier-free K-loop, packed bf16x4 stores, padded emb LDS.
// scan_mfma:   16 trees/block x 512 blocks (2 blocks/CU -> 2 waves/SIMD to
//              interleave the serial chains), 15 cs steps + cb combine, hi/lo
//              split MFMA, weights register-resident, fused final dot.

typedef __bf16 bf16x8 __attribute__((ext_vector_type(8)));
typedef __bf16 bf16x4 __attribute__((ext_vector_type(4)));
typedef float  f32x4  __attribute__((ext_vector_type(4)));

__global__ __launch_bounds__(256) void prep_kernel(
    const float* __restrict__ embedding,
    const float* __restrict__ leaf_end_W, const float* __restrict__ leaf_end_b,
    const float* __restrict__ lc_W1, const float* __restrict__ lc_W2,
    const float* __restrict__ nf_W1, const float* __restrict__ nf_W2,
    const float* __restrict__ cs_W1, const float* __restrict__ cs_W2,
    const float* __restrict__ cb_W1, const float* __restrict__ cb_W2,
    const float* __restrict__ ff_W1, const float* __restrict__ ff_b1,
    const float* __restrict__ ff_W2, const float* __restrict__ ff_b2,
    const float* __restrict__ ts_W, const float* __restrict__ ts_b,
    __bf16* __restrict__ lcW1T, __bf16* __restrict__ nfW1T,
    __bf16* __restrict__ lcW2T, __bf16* __restrict__ nfW2T,
    __bf16* __restrict__ emb_bf, float* __restrict__ endvec,
    __bf16* __restrict__ csW1Th, __bf16* __restrict__ csW1Tl,
    __bf16* __restrict__ cbW1Th, __bf16* __restrict__ cbW1Tl,
    __bf16* __restrict__ csW2Th, __bf16* __restrict__ csW2Tl,
    __bf16* __restrict__ cbW2Th, __bf16* __restrict__ cbW2Tl,
    float* __restrict__ vfin, float* __restrict__ cfin)
{
    const int id = blockIdx.x * 256 + threadIdx.x;
    if (id < 61440) {                        // lc_W1[k][n] read coalesced
        const int k = id >> 7, n = id & 127;
        lcW1T[n * 480 + k] = (__bf16)lc_W1[id];
    } else if (id < 122880) {
        const int e = id - 61440;
        const int k = e >> 7, n = e & 127;
        nfW1T[n * 480 + k] = (__bf16)nf_W1[e];
    } else if (id < 126976) {                // lc_W2[k][n] read coalesced
        const int e = id - 122880;
        const int k = e >> 5, n = e & 31;
        lcW2T[n * 128 + k] = (__bf16)lc_W2[e];
    } else if (id < 131072) {
        const int e = id - 126976;
        const int k = e >> 5, n = e & 31;
        nfW2T[n * 128 + k] = (__bf16)nf_W2[e];
    } else if (id < 134272) {
        emb_bf[id - 131072] = (__bf16)embedding[id - 131072];
    } else if (id < 134304) {                // endvec = emb[1] @ leaf_end_W + b
        const int c = id - 134272;
        float a = leaf_end_b[c];
        #pragma unroll
        for (int d = 0; d < 16; ++d) a = fmaf(embedding[16 + d], leaf_end_W[d * 32 + c], a);
        endvec[c] = a;
    } else if (id < 142496) {                // cs_W1 hi/lo  [64][128] -> T[128][64]
        const int e = id - 134304;
        const int k = e >> 7, n = e & 127;
        const float v = cs_W1[e];
        const __bf16 h = (__bf16)v;
        csW1Th[n * 64 + k] = h; csW1Tl[n * 64 + k] = (__bf16)(v - (float)h);
    } else if (id < 150688) {                // cb_W1 hi/lo
        const int e = id - 142496;
        const int k = e >> 7, n = e & 127;
        const float v = cb_W1[e];
        const __bf16 h = (__bf16)v;
        cbW1Th[n * 64 + k] = h; cbW1Tl[n * 64 + k] = (__bf16)(v - (float)h);
    } else if (id < 154784) {                // cs_W2 hi/lo  [128][32] -> T[32][128]
        const int e = id - 150688;
        const int k = e >> 5, n = e & 31;
        const float v = cs_W2[e];
        const __bf16 h = (__bf16)v;
        csW2Th[n * 128 + k] = h; csW2Tl[n * 128 + k] = (__bf16)(v - (float)h);
    } else if (id < 158880) {                // cb_W2 hi/lo
        const int e = id - 154784;
        const int k = e >> 5, n = e & 31;
        const float v = cb_W2[e];
        const __bf16 h = (__bf16)v;
        cbW2Th[n * 128 + k] = h; cbW2Tl[n * 128 + k] = (__bf16)(v - (float)h);
    } else if (id < 158912) {                // vfin[c] = ff_W1[c] . (ff_W2 @ ts_W)
        const int c = id - 158880;
        float w2t[32];
        #pragma unroll
        for (int k = 0; k < 32; ++k) {
            float a = 0.f;
            for (int j = 0; j < 32; ++j) a = fmaf(ff_W2[k * 32 + j], ts_W[j], a);
            w2t[k] = a;
        }
        float a = 0.f;
        #pragma unroll
        for (int k = 0; k < 32; ++k) a = fmaf(ff_W1[c * 32 + k], w2t[k], a);
        vfin[c] = a;
    } else if (id == 158912) {
        float a = ts_b[0];
        for (int j = 0; j < 32; ++j) a = fmaf(ff_b2[j], ts_W[j], a);
        for (int k = 0; k < 32; ++k) {
            float w2t = 0.f;
            for (int j = 0; j < 32; ++j) w2t = fmaf(ff_W2[k * 32 + j], ts_W[j], w2t);
            a = fmaf(ff_b1[k], w2t, a);
        }
        cfin[0] = a;
    }
}

// 64 rows/block: leaf blocks 0..2047 (131072 leaf rows), node blocks 2048..2175.
// Swapped operands: A = weights (m = out-col), B = gathered rows (n = row).
__global__ __launch_bounds__(256, 4) void mlp1_mfma(
    const int* __restrict__ trees,
    const float* __restrict__ lstm,
    const __bf16* __restrict__ lcW1T, const __bf16* __restrict__ nfW1T,
    const __bf16* __restrict__ lcW2T, const __bf16* __restrict__ nfW2T,
    const __bf16* __restrict__ emb_bf, const float* __restrict__ endvec,
    const float* __restrict__ lc_b1, const float* __restrict__ lc_b2,
    const float* __restrict__ nf_b1, const float* __restrict__ nf_b2,
    __bf16* __restrict__ childrenH, __bf16* __restrict__ childrenL,
    __bf16* __restrict__ node_tmpH, __bf16* __restrict__ node_tmpL)
{
    __shared__ __align__(16) __bf16 emb_s[200 * 24];   // padded stride 24 (48B)
    __shared__ __align__(16) __bf16 Hs[64][136];
    __shared__ float b1s[128], b2s[32], evs[32];
    __shared__ int   endf[64];

    const int tid = threadIdx.x;
    const int blk = blockIdx.x;
    const bool leaf = (blk < 2048);

    const __bf16* __restrict__ W1T = leaf ? lcW1T : nfW1T;
    const __bf16* __restrict__ W2T = leaf ? lcW2T : nfW2T;
    const float*  __restrict__ b1p = leaf ? lc_b1 : nf_b1;
    const float*  __restrict__ b2p = leaf ? lc_b2 : nf_b2;

    const int l  = tid & 63;
    const int w  = tid >> 6;        // wave 0..3
    const int lm = l & 15;
    const int kb = l >> 4;          // k sub-block 0..3
    const int wm = w >> 1;          // row half (rows wm*32..+31)
    const int wn = w & 1;           // W1-col half (cols wn*64..+63)

    // gather pointers for this wave's 2 row-tiles
    const int* tb[2];
    const float* lb[2];
    #pragma unroll
    for (int i = 0; i < 2; ++i) {
        const int r = wm * 32 + i * 16 + lm;
        int b, trow;
        if (leaf) { const int R = blk * 64 + r; b = R >> 4; trow = 1 + (R & 15); }
        else      { b = (blk - 2048) * 64 + r; trow = 0; }
        const int* t = trees + (b * 17 + trow) * 17;
        tb[i] = t;
        lb[i] = lstm + ((size_t)b * 64 + (size_t)t[16]) * 256;
    }

    // staging (padded embedding rows)
    for (int i = tid; i < 3200; i += 256) {
        const int row = i >> 4, col = i & 15;
        emb_s[row * 24 + col] = emb_bf[i];
    }
    if (tid < 128) b1s[tid] = b1p[tid];
    if (tid < 32)  { b2s[tid] = b2p[tid]; evs[tid] = leaf ? endvec[tid] : 0.f; }
    if (tid < 64) {
        if (leaf) {
            const int R = blk * 64 + tid;
            const int b = R >> 4, trow = 1 + (R & 15);
            endf[tid] = (trees[(b * 17 + trow) * 17 + 2] == 1);
        } else endf[tid] = 0;
    }

    f32x4 acc[2][4];
    #pragma unroll
    for (int i = 0; i < 2; ++i)
        #pragma unroll
        for (int j = 0; j < 4; ++j) acc[i][j] = (f32x4){0.f, 0.f, 0.f, 0.f};

    __syncthreads();

    // layer 1: 480 -> 128 in 15 K-chunks of 32. A = W1 cols, B = rows.
    #pragma unroll
    for (int c = 0; c < 15; ++c) {
        bf16x8 wfr[4];
        #pragma unroll
        for (int ct = 0; ct < 4; ++ct) {
            const int n = wn * 64 + ct * 16 + lm;
            wfr[ct] = *(const bf16x8*)(W1T + n * 480 + c * 32 + kb * 8);
        }
        bf16x8 bfr[2];
        if (c < 7) {
            #pragma unroll
            for (int i = 0; i < 2; ++i) {
                const int tok = tb[i][2 + 2 * c + (kb >> 1)];
                bfr[i] = *(const bf16x8*)(emb_s + tok * 24 + (kb & 1) * 8);
            }
        } else {
            #pragma unroll
            for (int i = 0; i < 2; ++i) {
                const float* p = lb[i] + (c - 7) * 32 + kb * 8;
                const float4 u = *(const float4*)p;
                const float4 v = *(const float4*)(p + 4);
                bf16x8 t;
                t[0] = (__bf16)u.x; t[1] = (__bf16)u.y; t[2] = (__bf16)u.z; t[3] = (__bf16)u.w;
                t[4] = (__bf16)v.x; t[5] = (__bf16)v.y; t[6] = (__bf16)v.z; t[7] = (__bf16)v.w;
                bfr[i] = t;
            }
        }
        #pragma unroll
        for (int i = 0; i < 2; ++i)
            #pragma unroll
            for (int ct = 0; ct < 4; ++ct)
                acc[i][ct] = __builtin_amdgcn_mfma_f32_16x16x32_bf16(wfr[ct], bfr[i], acc[i][ct], 0, 0, 0);
    }

    // D: col(lane&15) = row-in-tile, row(4*kb+rg) = W1-col -> packed 4-col store
    #pragma unroll
    for (int i = 0; i < 2; ++i)
        #pragma unroll
        for (int ct = 0; ct < 4; ++ct) {
            const int wcol = wn * 64 + ct * 16 + 4 * kb;
            bf16x4 pk;
            #pragma unroll
            for (int rg = 0; rg < 4; ++rg) {
                float v = acc[i][ct][rg] + b1s[wcol + rg];
                v = v > 0.f ? v : 0.f;
                pk[rg] = (__bf16)v;
            }
            *(bf16x4*)&Hs[wm * 32 + i * 16 + lm][wcol] = pk;
        }
    __syncthreads();

    // layer 2: 64x32. wave w: outcol tile jn=w&1, row-tiles {2*(w>>1)+i}.
    const int jn = w & 1, rb2 = 2 * (w >> 1);
    f32x4 acc2[2];
    acc2[0] = (f32x4){0.f, 0.f, 0.f, 0.f};
    acc2[1] = (f32x4){0.f, 0.f, 0.f, 0.f};

    #pragma unroll
    for (int kc = 0; kc < 4; ++kc) {
        const bf16x8 wf = *(const bf16x8*)(W2T + (jn * 16 + lm) * 128 + kc * 32 + kb * 8);
        #pragma unroll
        for (int i = 0; i < 2; ++i) {
            const bf16x8 hf = *(const bf16x8*)(&Hs[(rb2 + i) * 16 + lm][kc * 32 + kb * 8]);
            acc2[i] = __builtin_amdgcn_mfma_f32_16x16x32_bf16(wf, hf, acc2[i], 0, 0, 0);
        }
    }

    #pragma unroll
    for (int i = 0; i < 2; ++i) {
        const int orow = (rb2 + i) * 16 + lm;     // row within block
        const int ocol = jn * 16 + 4 * kb;        // +rg
        const bool isend = leaf && endf[orow];
        bf16x4 ph, pl;
        #pragma unroll
        for (int rg = 0; rg < 4; ++rg) {
            float v = acc2[i][rg] + b2s[ocol + rg];
            v = v > 0.f ? v : 0.f;
            if (isend) v = evs[ocol + rg];
            const __bf16 h = (__bf16)v;
            ph[rg] = h;
            pl[rg] = (__bf16)(v - (float)h);
        }
        if (leaf) {
            const size_t R = (size_t)blk * 64 + orow;
            *(bf16x4*)&childrenH[R * 32 + ocol] = ph;
            *(bf16x4*)&childrenL[R * 32 + ocol] = pl;
        } else {
            const size_t R = (size_t)(blk - 2048) * 64 + orow;
            *(bf16x4*)&node_tmpH[R * 32 + ocol] = ph;
            *(bf16x4*)&node_tmpL[R * 32 + ocol] = pl;
        }
    }
}

// 16 trees/block, 512 blocks (2 blocks/CU), 4 waves. Swapped operands; packed LDS IO.
__global__ __launch_bounds__(256) void scan_mfma(
    const __bf16* __restrict__ childrenH, const __bf16* __restrict__ childrenL,
    const __bf16* __restrict__ node_tmpH, const __bf16* __restrict__ node_tmpL,
    const __bf16* __restrict__ csW1Th, const __bf16* __restrict__ csW1Tl,
    const __bf16* __restrict__ csW2Th, const __bf16* __restrict__ csW2Tl,
    const __bf16* __restrict__ cbW1Th, const __bf16* __restrict__ cbW1Tl,
    const __bf16* __restrict__ cbW2Th, const __bf16* __restrict__ cbW2Tl,
    const float* __restrict__ cs_b1, const float* __restrict__ cs_b2,
    const float* __restrict__ cb_b1, const float* __restrict__ cb_b2,
    const float* __restrict__ vfin_g, const float* __restrict__ cfin_g,
    float* __restrict__ out)
{
    __shared__ __align__(16) __bf16 Xh[16][72], Xl[16][72];
    __shared__ __align__(16) __bf16 Hh[16][136], Hl[16][136];
    __shared__ float b1a[128], b1b[128], b2a[32], b2b[32], vfin[32];
    __shared__ float psum[2][16];
    __shared__ float cfin_s;

    const int tid = threadIdx.x;
    const int l = tid & 63, w = tid >> 6;      // 4 waves
    const int lm = l & 15, kb = l >> 4;

    if (tid < 128)      { b1a[tid] = cs_b1[tid]; b1b[tid] = cb_b1[tid]; }
    else if (tid < 160) { b2a[tid - 128] = cs_b2[tid - 128]; b2b[tid - 128] = cb_b2[tid - 128]; }
    else if (tid < 192) { vfin[tid - 160] = vfin_g[tid - 160]; }
    else if (tid == 192) cfin_s = cfin_g[0];

    // layer1 weights (A-frags): wave w owns cols [w*32, +32): 2 tiles x 2 K-chunks
    bf16x8 W1r[2][2][2];   // [nt][kc][hi/lo]
    #pragma unroll
    for (int nt = 0; nt < 2; ++nt)
        #pragma unroll
        for (int kc = 0; kc < 2; ++kc) {
            const int n = w * 32 + nt * 16 + lm;
            W1r[nt][kc][0] = *(const bf16x8*)(csW1Th + n * 64 + kc * 32 + kb * 8);
            W1r[nt][kc][1] = *(const bf16x8*)(csW1Tl + n * 64 + kc * 32 + kb * 8);
        }
    // layer2 weights: waves 0-1 own outcol tile w; 4 K-chunks
    bf16x8 W2r[4][2];
    if (w < 2) {
        const int n2 = w * 16 + lm;
        #pragma unroll
        for (int kc = 0; kc < 4; ++kc) {
            W2r[kc][0] = *(const bf16x8*)(csW2Th + n2 * 128 + kc * 32 + kb * 8);
            W2r[kc][1] = *(const bf16x8*)(csW2Tl + n2 * 128 + kc * 32 + kb * 8);
        }
    }

    const size_t base = (size_t)blockIdx.x * 16;
    const int tt = (tid & 127) >> 3, c4 = (tid & 7) * 4;   // staging role (tid<128)

    if (tid < 128) {
        const size_t o0 = ((base + tt) * 16 + 0) * 32 + c4;
        const size_t o1 = ((base + tt) * 16 + 1) * 32 + c4;
        *(bf16x4*)&Xh[tt][c4]      = *(const bf16x4*)(childrenH + o0);
        *(bf16x4*)&Xl[tt][c4]      = *(const bf16x4*)(childrenL + o0);
        *(bf16x4*)&Xh[tt][32 + c4] = *(const bf16x4*)(childrenH + o1);
        *(bf16x4*)&Xl[tt][32 + c4] = *(const bf16x4*)(childrenL + o1);
    }
    __syncthreads();

    #pragma unroll 1
    for (int it = 1; it <= 16; ++it) {
        const bool fin = (it == 16);
        if (fin) {   // swap to cb weights (last iteration)
            #pragma unroll
            for (int nt = 0; nt < 2; ++nt)
                #pragma unroll
                for (int kc = 0; kc < 2; ++kc) {
                    const int n = w * 32 + nt * 16 + lm;
                    W1r[nt][kc][0] = *(const bf16x8*)(cbW1Th + n * 64 + kc * 32 + kb * 8);
                    W1r[nt][kc][1] = *(const bf16x8*)(cbW1Tl + n * 64 + kc * 32 + kb * 8);
                }
            if (w < 2) {
                const int n2 = w * 16 + lm;
                #pragma unroll
                for (int kc = 0; kc < 4; ++kc) {
                    W2r[kc][0] = *(const bf16x8*)(cbW2Th + n2 * 128 + kc * 32 + kb * 8);
                    W2r[kc][1] = *(const bf16x8*)(cbW2Tl + n2 * 128 + kc * 32 + kb * 8);
                }
            }
        }
        const float* __restrict__ b1c = fin ? b1b : b1a;
        const float* __restrict__ b2c = fin ? b2b : b2a;

        // prefetch next child (or node_tmp before the combine step)
        bf16x4 pfh, pfl;
        const int pfmode = (it < 15) ? 1 : (it == 15 ? 2 : 0);
        if (tid < 128) {
            if (pfmode == 1) {
                const size_t o = ((base + tt) * 16 + (it + 1)) * 32 + c4;
                pfh = *(const bf16x4*)(childrenH + o);
                pfl = *(const bf16x4*)(childrenL + o);
            } else if (pfmode == 2) {
                const size_t o = (base + tt) * 32 + c4;
                pfh = *(const bf16x4*)(node_tmpH + o);
                pfl = *(const bf16x4*)(node_tmpL + o);
            }
        }

        // ---- layer 1: A=W1 (cols w*32..), B=X (16 trees, one tile) ----
        bf16x8 xh[2], xl[2];
        #pragma unroll
        for (int kc = 0; kc < 2; ++kc) {
            xh[kc] = *(const bf16x8*)&Xh[lm][kc * 32 + kb * 8];
            xl[kc] = *(const bf16x8*)&Xl[lm][kc * 32 + kb * 8];
        }
        f32x4 a1[2];
        #pragma unroll
        for (int nt = 0; nt < 2; ++nt) {
            a1[nt] = (f32x4){0.f, 0.f, 0.f, 0.f};
            #pragma unroll
            for (int kc = 0; kc < 2; ++kc) {
                a1[nt] = __builtin_amdgcn_mfma_f32_16x16x32_bf16(W1r[nt][kc][0], xh[kc], a1[nt], 0, 0, 0);
                a1[nt] = __builtin_amdgcn_mfma_f32_16x16x32_bf16(W1r[nt][kc][0], xl[kc], a1[nt], 0, 0, 0);
                a1[nt] = __builtin_amdgcn_mfma_f32_16x16x32_bf16(W1r[nt][kc][1], xh[kc], a1[nt], 0, 0, 0);
            }
        }
        // D: col = tree, row = W1-col -> packed stores
        #pragma unroll
        for (int nt = 0; nt < 2; ++nt) {
            const int wcol = w * 32 + nt * 16 + 4 * kb;
            bf16x4 ph, pl;
            #pragma unroll
            for (int rg = 0; rg < 4; ++rg) {
                float v = a1[nt][rg] + b1c[wcol + rg];
                v = v > 0.f ? v : 0.f;
                const __bf16 h = (__bf16)v;
                ph[rg] = h;
                pl[rg] = (__bf16)(v - (float)h);
            }
            *(bf16x4*)&Hh[lm][wcol] = ph;
            *(bf16x4*)&Hl[lm][wcol] = pl;
        }
        __syncthreads();

        // ---- layer 2: A=W2, B=H (waves 0-1; wave w -> outcols w*16..) ----
        f32x4 a2 = (f32x4){0.f, 0.f, 0.f, 0.f};
        if (w < 2) {
            #pragma unroll
            for (int kc = 0; kc < 4; ++kc) {
                const bf16x8 hh = *(const bf16x8*)&Hh[lm][kc * 32 + kb * 8];
                const bf16x8 hl = *(const bf16x8*)&Hl[lm][kc * 32 + kb * 8];
                a2 = __builtin_amdgcn_mfma_f32_16x16x32_bf16(W2r[kc][0], hh, a2, 0, 0, 0);
                a2 = __builtin_amdgcn_mfma_f32_16x16x32_bf16(W2r[kc][0], hl, a2, 0, 0, 0);
                a2 = __builtin_amdgcn_mfma_f32_16x16x32_bf16(W2r[kc][1], hh, a2, 0, 0, 0);
            }
        }

        if (!fin) {
            // new carry: tree = lm, feats w*16+4kb..+3 (packed), waves 0-1 only
            const int cb_ = (it == 15) ? 32 : 0;
            if (w < 2) {
                const int ocol = w * 16 + 4 * kb;
                bf16x4 ph, pl;
                #pragma unroll
                for (int rg = 0; rg < 4; ++rg) {
                    float v = a2[rg] + b2c[ocol + rg];
                    v = v > 0.f ? v : 0.f;
                    const __bf16 h = (__bf16)v;
                    ph[rg] = h;
                    pl[rg] = (__bf16)(v - (float)h);
                }
                *(bf16x4*)&Xh[lm][cb_ + ocol] = ph;
                *(bf16x4*)&Xl[lm][cb_ + ocol] = pl;
            }
            if (tid < 128 && pfmode) {
                const int dst = (pfmode == 2) ? 0 : 32;
                *(bf16x4*)&Xh[tt][dst + c4] = pfh;
                *(bf16x4*)&Xl[tt][dst + c4] = pfl;
            }
            __syncthreads();
        } else {
            // fused final linear: out = tree_sum . vfin + cfin
            if (w < 2) {
                const int ocol = w * 16 + 4 * kb;
                float p = 0.f;
                #pragma unroll
                for (int rg = 0; rg < 4; ++rg) {
                    float v = a2[rg] + b2c[ocol + rg];
                    v = v > 0.f ? v : 0.f;
                    p = fmaf(v, vfin[ocol + rg], p);
                }
                p += __shfl_xor(p, 16, 64);
                p += __shfl_xor(p, 32, 64);
                if (kb == 0) psum[w][lm] = p;
            }
            __syncthreads();
            if (tid < 16) out[base + tid] = cfin_s + psum[0][tid] + psum[1][tid];
        }
    }
}

extern "C" void kernel_launch(void* const* d_in, const int* in_sizes, int n_in,
                              void* d_out, int out_size, void* d_ws, size_t ws_size,
                              hipStream_t stream) {
    const int*   trees      = (const int*)d_in[0];
    const float* lstm       = (const float*)d_in[1];
    const float* embedding  = (const float*)d_in[4];
    const float* leaf_end_W = (const float*)d_in[5];
    const float* leaf_end_b = (const float*)d_in[6];
    const float* lc_W1 = (const float*)d_in[7];
    const float* lc_b1 = (const float*)d_in[8];
    const float* lc_W2 = (const float*)d_in[9];
    const float* lc_b2 = (const float*)d_in[10];
    const float* cs_W1 = (const float*)d_in[11];
    const float* cs_b1 = (const float*)d_in[12];
    const float* cs_W2 = (const float*)d_in[13];
    const float* cs_b2 = (const float*)d_in[14];
    const float* nf_W1 = (const float*)d_in[15];
    const float* nf_b1 = (const float*)d_in[16];
    const float* nf_W2 = (const float*)d_in[17];
    const float* nf_b2 = (const float*)d_in[18];
    const float* cb_W1 = (const float*)d_in[19];
    const float* cb_b1 = (const float*)d_in[20];
    const float* cb_W2 = (const float*)d_in[21];
    const float* cb_b2 = (const float*)d_in[22];
    const float* ff_W1 = (const float*)d_in[23];
    const float* ff_b1 = (const float*)d_in[24];
    const float* ff_W2 = (const float*)d_in[25];
    const float* ff_b2 = (const float*)d_in[26];
    const float* ts_W  = (const float*)d_in[27];
    const float* ts_b  = (const float*)d_in[28];

    char* ws = (char*)d_ws;
    __bf16* childrenH = (__bf16*)ws;                             // 8 MiB
    __bf16* childrenL = (__bf16*)(ws + 8388608);                 // 8 MiB
    __bf16* node_tmpH = (__bf16*)(ws + 16777216);                // 0.5 MiB
    __bf16* node_tmpL = (__bf16*)(ws + 17301504);                // 0.5 MiB
    __bf16* lcW1T    = (__bf16*)(ws + 17825792);
    __bf16* nfW1T    = (__bf16*)(ws + 17948672);
    __bf16* lcW2T    = (__bf16*)(ws + 18071552);
    __bf16* nfW2T    = (__bf16*)(ws + 18079744);
    __bf16* emb_bf   = (__bf16*)(ws + 18087936);
    float*  endvec   = (float*)(ws + 18094336);
    __bf16* csW1Th   = (__bf16*)(ws + 18094464);
    __bf16* csW1Tl   = (__bf16*)(ws + 18110848);
    __bf16* cbW1Th   = (__bf16*)(ws + 18127232);
    __bf16* cbW1Tl   = (__bf16*)(ws + 18143616);
    __bf16* csW2Th   = (__bf16*)(ws + 18160000);
    __bf16* csW2Tl   = (__bf16*)(ws + 18168192);
    __bf16* cbW2Th   = (__bf16*)(ws + 18176384);
    __bf16* cbW2Tl   = (__bf16*)(ws + 18184576);
    float*  vfin     = (float*)(ws + 18192768);
    float*  cfin     = (float*)(ws + 18192896);
    float*  outp     = (float*)d_out;

    prep_kernel<<<dim3(621), dim3(256), 0, stream>>>(
        embedding, leaf_end_W, leaf_end_b, lc_W1, lc_W2, nf_W1, nf_W2,
        cs_W1, cs_W2, cb_W1, cb_W2, ff_W1, ff_b1, ff_W2, ff_b2, ts_W, ts_b,
        lcW1T, nfW1T, lcW2T, nfW2T, emb_bf, endvec,
        csW1Th, csW1Tl, cbW1Th, cbW1Tl, csW2Th, csW2Tl, cbW2Th, cbW2Tl,
        vfin, cfin);

    mlp1_mfma<<<dim3(2176), dim3(256), 0, stream>>>(
        trees, lstm, lcW1T, nfW1T, lcW2T, nfW2T, emb_bf, endvec,
        lc_b1, lc_b2, nf_b1, nf_b2, childrenH, childrenL, node_tmpH, node_tmpL);

    scan_mfma<<<dim3(512), dim3(256), 0, stream>>>(
        childrenH, childrenL, node_tmpH, node_tmpL,
        csW1Th, csW1Tl, csW2Th, csW2Tl, cbW1Th, cbW1Tl, cbW2Th, cbW2Tl,
        cs_b1, cs_b2, cb_b1, cb_b2, vfin, cfin, outp);
}

// Round 11
// 126.374 us; speedup vs baseline: 1.1228x; 1.0095x over previous
//
#include <hip/hip_runtime.h>
#include <cstddef>

// B=8192 trees, 16 leaves + 1 root. FEAT=480 (14 tok x 16 emb + 256 lstm).
// prep_kernel: read-coalesced bf16 transposes (lc/nf W1/W2, hi/lo cs/cb), emb,
//              endvec, vfin/cfin collapse of the final linear chain.
// mlp1_mfma:   R6-exact: 64 rows/block, 2 row-tiles x 1 col-half per wave,
//              barrier-free K-loop, packed bf16x4 stores, padded emb LDS.
// scan_mfma:   R6 config (32 trees/block x 256 blocks x 4 waves) with shorter
//              serial chains: H kept bf16-hi only (X stays hi/lo), and all MFMA
//              accumulator chains split in two (depth 3 / depth 4) + f32 add.

typedef __bf16 bf16x8 __attribute__((ext_vector_type(8)));
typedef __bf16 bf16x4 __attribute__((ext_vector_type(4)));
typedef float  f32x4  __attribute__((ext_vector_type(4)));

__global__ __launch_bounds__(256) void prep_kernel(
    const float* __restrict__ embedding,
    const float* __restrict__ leaf_end_W, const float* __restrict__ leaf_end_b,
    const float* __restrict__ lc_W1, const float* __restrict__ lc_W2,
    const float* __restrict__ nf_W1, const float* __restrict__ nf_W2,
    const float* __restrict__ cs_W1, const float* __restrict__ cs_W2,
    const float* __restrict__ cb_W1, const float* __restrict__ cb_W2,
    const float* __restrict__ ff_W1, const float* __restrict__ ff_b1,
    const float* __restrict__ ff_W2, const float* __restrict__ ff_b2,
    const float* __restrict__ ts_W, const float* __restrict__ ts_b,
    __bf16* __restrict__ lcW1T, __bf16* __restrict__ nfW1T,
    __bf16* __restrict__ lcW2T, __bf16* __restrict__ nfW2T,
    __bf16* __restrict__ emb_bf, float* __restrict__ endvec,
    __bf16* __restrict__ csW1Th, __bf16* __restrict__ csW1Tl,
    __bf16* __restrict__ cbW1Th, __bf16* __restrict__ cbW1Tl,
    __bf16* __restrict__ csW2Th, __bf16* __restrict__ csW2Tl,
    __bf16* __restrict__ cbW2Th, __bf16* __restrict__ cbW2Tl,
    float* __restrict__ vfin, float* __restrict__ cfin)
{
    const int id = blockIdx.x * 256 + threadIdx.x;
    if (id < 61440) {                        // lc_W1[k][n] read coalesced
        const int k = id >> 7, n = id & 127;
        lcW1T[n * 480 + k] = (__bf16)lc_W1[id];
    } else if (id < 122880) {
        const int e = id - 61440;
        const int k = e >> 7, n = e & 127;
        nfW1T[n * 480 + k] = (__bf16)nf_W1[e];
    } else if (id < 126976) {                // lc_W2[k][n] read coalesced
        const int e = id - 122880;
        const int k = e >> 5, n = e & 31;
        lcW2T[n * 128 + k] = (__bf16)lc_W2[e];
    } else if (id < 131072) {
        const int e = id - 126976;
        const int k = e >> 5, n = e & 31;
        nfW2T[n * 128 + k] = (__bf16)nf_W2[e];
    } else if (id < 134272) {
        emb_bf[id - 131072] = (__bf16)embedding[id - 131072];
    } else if (id < 134304) {                // endvec = emb[1] @ leaf_end_W + b
        const int c = id - 134272;
        float a = leaf_end_b[c];
        #pragma unroll
        for (int d = 0; d < 16; ++d) a = fmaf(embedding[16 + d], leaf_end_W[d * 32 + c], a);
        endvec[c] = a;
    } else if (id < 142496) {                // cs_W1 hi/lo  [64][128] -> T[128][64]
        const int e = id - 134304;
        const int k = e >> 7, n = e & 127;
        const float v = cs_W1[e];
        const __bf16 h = (__bf16)v;
        csW1Th[n * 64 + k] = h; csW1Tl[n * 64 + k] = (__bf16)(v - (float)h);
    } else if (id < 150688) {                // cb_W1 hi/lo
        const int e = id - 142496;
        const int k = e >> 7, n = e & 127;
        const float v = cb_W1[e];
        const __bf16 h = (__bf16)v;
        cbW1Th[n * 64 + k] = h; cbW1Tl[n * 64 + k] = (__bf16)(v - (float)h);
    } else if (id < 154784) {                // cs_W2 hi/lo  [128][32] -> T[32][128]
        const int e = id - 150688;
        const int k = e >> 5, n = e & 31;
        const float v = cs_W2[e];
        const __bf16 h = (__bf16)v;
        csW2Th[n * 128 + k] = h; csW2Tl[n * 128 + k] = (__bf16)(v - (float)h);
    } else if (id < 158880) {                // cb_W2 hi/lo
        const int e = id - 154784;
        const int k = e >> 5, n = e & 31;
        const float v = cb_W2[e];
        const __bf16 h = (__bf16)v;
        cbW2Th[n * 128 + k] = h; cbW2Tl[n * 128 + k] = (__bf16)(v - (float)h);
    } else if (id < 158912) {                // vfin[c] = ff_W1[c] . (ff_W2 @ ts_W)
        const int c = id - 158880;
        float w2t[32];
        #pragma unroll
        for (int k = 0; k < 32; ++k) {
            float a = 0.f;
            for (int j = 0; j < 32; ++j) a = fmaf(ff_W2[k * 32 + j], ts_W[j], a);
            w2t[k] = a;
        }
        float a = 0.f;
        #pragma unroll
        for (int k = 0; k < 32; ++k) a = fmaf(ff_W1[c * 32 + k], w2t[k], a);
        vfin[c] = a;
    } else if (id == 158912) {
        float a = ts_b[0];
        for (int j = 0; j < 32; ++j) a = fmaf(ff_b2[j], ts_W[j], a);
        for (int k = 0; k < 32; ++k) {
            float w2t = 0.f;
            for (int j = 0; j < 32; ++j) w2t = fmaf(ff_W2[k * 32 + j], ts_W[j], w2t);
            a = fmaf(ff_b1[k], w2t, a);
        }
        cfin[0] = a;
    }
}

// 64 rows/block: leaf blocks 0..2047 (131072 leaf rows), node blocks 2048..2175.
// Swapped operands: A = weights (m = out-col), B = gathered rows (n = row).
__global__ __launch_bounds__(256, 4) void mlp1_mfma(
    const int* __restrict__ trees,
    const float* __restrict__ lstm,
    const __bf16* __restrict__ lcW1T, const __bf16* __restrict__ nfW1T,
    const __bf16* __restrict__ lcW2T, const __bf16* __restrict__ nfW2T,
    const __bf16* __restrict__ emb_bf, const float* __restrict__ endvec,
    const float* __restrict__ lc_b1, const float* __restrict__ lc_b2,
    const float* __restrict__ nf_b1, const float* __restrict__ nf_b2,
    __bf16* __restrict__ childrenH, __bf16* __restrict__ childrenL,
    __bf16* __restrict__ node_tmpH, __bf16* __restrict__ node_tmpL)
{
    __shared__ __align__(16) __bf16 emb_s[200 * 24];   // padded stride 24 (48B)
    __shared__ __align__(16) __bf16 Hs[64][136];
    __shared__ float b1s[128], b2s[32], evs[32];
    __shared__ int   endf[64];

    const int tid = threadIdx.x;
    const int blk = blockIdx.x;
    const bool leaf = (blk < 2048);

    const __bf16* __restrict__ W1T = leaf ? lcW1T : nfW1T;
    const __bf16* __restrict__ W2T = leaf ? lcW2T : nfW2T;
    const float*  __restrict__ b1p = leaf ? lc_b1 : nf_b1;
    const float*  __restrict__ b2p = leaf ? lc_b2 : nf_b2;

    const int l  = tid & 63;
    const int w  = tid >> 6;        // wave 0..3
    const int lm = l & 15;
    const int kb = l >> 4;          // k sub-block 0..3
    const int wm = w >> 1;          // row half (rows wm*32..+31)
    const int wn = w & 1;           // W1-col half (cols wn*64..+63)

    // gather pointers for this wave's 2 row-tiles
    const int* tb[2];
    const float* lb[2];
    #pragma unroll
    for (int i = 0; i < 2; ++i) {
        const int r = wm * 32 + i * 16 + lm;
        int b, trow;
        if (leaf) { const int R = blk * 64 + r; b = R >> 4; trow = 1 + (R & 15); }
        else      { b = (blk - 2048) * 64 + r; trow = 0; }
        const int* t = trees + (b * 17 + trow) * 17;
        tb[i] = t;
        lb[i] = lstm + ((size_t)b * 64 + (size_t)t[16]) * 256;
    }

    // staging (padded embedding rows)
    for (int i = tid; i < 3200; i += 256) {
        const int row = i >> 4, col = i & 15;
        emb_s[row * 24 + col] = emb_bf[i];
    }
    if (tid < 128) b1s[tid] = b1p[tid];
    if (tid < 32)  { b2s[tid] = b2p[tid]; evs[tid] = leaf ? endvec[tid] : 0.f; }
    if (tid < 64) {
        if (leaf) {
            const int R = blk * 64 + tid;
            const int b = R >> 4, trow = 1 + (R & 15);
            endf[tid] = (trees[(b * 17 + trow) * 17 + 2] == 1);
        } else endf[tid] = 0;
    }

    f32x4 acc[2][4];
    #pragma unroll
    for (int i = 0; i < 2; ++i)
        #pragma unroll
        for (int j = 0; j < 4; ++j) acc[i][j] = (f32x4){0.f, 0.f, 0.f, 0.f};

    __syncthreads();

    // layer 1: 480 -> 128 in 15 K-chunks of 32. A = W1 cols, B = rows.
    #pragma unroll
    for (int c = 0; c < 15; ++c) {
        bf16x8 wfr[4];
        #pragma unroll
        for (int ct = 0; ct < 4; ++ct) {
            const int n = wn * 64 + ct * 16 + lm;
            wfr[ct] = *(const bf16x8*)(W1T + n * 480 + c * 32 + kb * 8);
        }
        bf16x8 bfr[2];
        if (c < 7) {
            #pragma unroll
            for (int i = 0; i < 2; ++i) {
                const int tok = tb[i][2 + 2 * c + (kb >> 1)];
                bfr[i] = *(const bf16x8*)(emb_s + tok * 24 + (kb & 1) * 8);
            }
        } else {
            #pragma unroll
            for (int i = 0; i < 2; ++i) {
                const float* p = lb[i] + (c - 7) * 32 + kb * 8;
                const float4 u = *(const float4*)p;
                const float4 v = *(const float4*)(p + 4);
                bf16x8 t;
                t[0] = (__bf16)u.x; t[1] = (__bf16)u.y; t[2] = (__bf16)u.z; t[3] = (__bf16)u.w;
                t[4] = (__bf16)v.x; t[5] = (__bf16)v.y; t[6] = (__bf16)v.z; t[7] = (__bf16)v.w;
                bfr[i] = t;
            }
        }
        #pragma unroll
        for (int i = 0; i < 2; ++i)
            #pragma unroll
            for (int ct = 0; ct < 4; ++ct)
                acc[i][ct] = __builtin_amdgcn_mfma_f32_16x16x32_bf16(wfr[ct], bfr[i], acc[i][ct], 0, 0, 0);
    }

    // D: col(lane&15) = row-in-tile, row(4*kb+rg) = W1-col -> packed 4-col store
    #pragma unroll
    for (int i = 0; i < 2; ++i)
        #pragma unroll
        for (int ct = 0; ct < 4; ++ct) {
            const int wcol = wn * 64 + ct * 16 + 4 * kb;
            bf16x4 pk;
            #pragma unroll
            for (int rg = 0; rg < 4; ++rg) {
                float v = acc[i][ct][rg] + b1s[wcol + rg];
                v = v > 0.f ? v : 0.f;
                pk[rg] = (__bf16)v;
            }
            *(bf16x4*)&Hs[wm * 32 + i * 16 + lm][wcol] = pk;
        }
    __syncthreads();

    // layer 2: 64x32. wave w: outcol tile jn=w&1, row-tiles {2*(w>>1)+i}.
    const int jn = w & 1, rb2 = 2 * (w >> 1);
    f32x4 acc2[2];
    acc2[0] = (f32x4){0.f, 0.f, 0.f, 0.f};
    acc2[1] = (f32x4){0.f, 0.f, 0.f, 0.f};

    #pragma unroll
    for (int kc = 0; kc < 4; ++kc) {
        const bf16x8 wf = *(const bf16x8*)(W2T + (jn * 16 + lm) * 128 + kc * 32 + kb * 8);
        #pragma unroll
        for (int i = 0; i < 2; ++i) {
            const bf16x8 hf = *(const bf16x8*)(&Hs[(rb2 + i) * 16 + lm][kc * 32 + kb * 8]);
            acc2[i] = __builtin_amdgcn_mfma_f32_16x16x32_bf16(wf, hf, acc2[i], 0, 0, 0);
        }
    }

    #pragma unroll
    for (int i = 0; i < 2; ++i) {
        const int orow = (rb2 + i) * 16 + lm;     // row within block
        const int ocol = jn * 16 + 4 * kb;        // +rg
        const bool isend = leaf && endf[orow];
        bf16x4 ph, pl;
        #pragma unroll
        for (int rg = 0; rg < 4; ++rg) {
            float v = acc2[i][rg] + b2s[ocol + rg];
            v = v > 0.f ? v : 0.f;
            if (isend) v = evs[ocol + rg];
            const __bf16 h = (__bf16)v;
            ph[rg] = h;
            pl[rg] = (__bf16)(v - (float)h);
        }
        if (leaf) {
            const size_t R = (size_t)blk * 64 + orow;
            *(bf16x4*)&childrenH[R * 32 + ocol] = ph;
            *(bf16x4*)&childrenL[R * 32 + ocol] = pl;
        } else {
            const size_t R = (size_t)(blk - 2048) * 64 + orow;
            *(bf16x4*)&node_tmpH[R * 32 + ocol] = ph;
            *(bf16x4*)&node_tmpL[R * 32 + ocol] = pl;
        }
    }
}

// 32 trees/block, 256 blocks, 4 waves. H bf16-hi only; split accumulator chains.
__global__ __launch_bounds__(256) void scan_mfma(
    const __bf16* __restrict__ childrenH, const __bf16* __restrict__ childrenL,
    const __bf16* __restrict__ node_tmpH, const __bf16* __restrict__ node_tmpL,
    const __bf16* __restrict__ csW1Th, const __bf16* __restrict__ csW1Tl,
    const __bf16* __restrict__ csW2Th, const __bf16* __restrict__ csW2Tl,
    const __bf16* __restrict__ cbW1Th, const __bf16* __restrict__ cbW1Tl,
    const __bf16* __restrict__ cbW2Th, const __bf16* __restrict__ cbW2Tl,
    const float* __restrict__ cs_b1, const float* __restrict__ cs_b2,
    const float* __restrict__ cb_b1, const float* __restrict__ cb_b2,
    const float* __restrict__ vfin_g, const float* __restrict__ cfin_g,
    float* __restrict__ out)
{
    __shared__ __align__(16) __bf16 Xh[32][72], Xl[32][72];
    __shared__ __align__(16) __bf16 Hh[32][136];
    __shared__ float b1a[128], b1b[128], b2a[32], b2b[32], vfin[32];
    __shared__ float psum[2][32];
    __shared__ float cfin_s;

    const int tid = threadIdx.x;
    const int l = tid & 63, w = tid >> 6;      // 4 waves
    const int lm = l & 15, kb = l >> 4;

    if (tid < 128)      { b1a[tid] = cs_b1[tid]; b1b[tid] = cb_b1[tid]; }
    else if (tid < 160) { b2a[tid - 128] = cs_b2[tid - 128]; b2b[tid - 128] = cb_b2[tid - 128]; }
    else if (tid < 192) { vfin[tid - 160] = vfin_g[tid - 160]; }
    else if (tid == 192) cfin_s = cfin_g[0];

    // layer1 weights (A-frags): wave w owns cols [w*32, +32): 2 tiles x 2 K-chunks
    bf16x8 W1r[2][2][2];   // [nt][kc][hi/lo]
    #pragma unroll
    for (int nt = 0; nt < 2; ++nt)
        #pragma unroll
        for (int kc = 0; kc < 2; ++kc) {
            const int n = w * 32 + nt * 16 + lm;
            W1r[nt][kc][0] = *(const bf16x8*)(csW1Th + n * 64 + kc * 32 + kb * 8);
            W1r[nt][kc][1] = *(const bf16x8*)(csW1Tl + n * 64 + kc * 32 + kb * 8);
        }
    // layer2 weights: wave w owns outcols (w&1)*16.. ; 4 K-chunks
    bf16x8 W2r[4][2];
    {
        const int n2 = (w & 1) * 16 + lm;
        #pragma unroll
        for (int kc = 0; kc < 4; ++kc) {
            W2r[kc][0] = *(const bf16x8*)(csW2Th + n2 * 128 + kc * 32 + kb * 8);
            W2r[kc][1] = *(const bf16x8*)(csW2Tl + n2 * 128 + kc * 32 + kb * 8);
        }
    }

    const size_t base = (size_t)blockIdx.x * 32;
    const int tt = tid >> 3, c4 = (tid & 7) * 4;    // staging: tree tt, cols c4..

    {
        const size_t o0 = ((base + tt) * 16 + 0) * 32 + c4;
        const size_t o1 = ((base + tt) * 16 + 1) * 32 + c4;
        *(bf16x4*)&Xh[tt][c4]      = *(const bf16x4*)(childrenH + o0);
        *(bf16x4*)&Xl[tt][c4]      = *(const bf16x4*)(childrenL + o0);
        *(bf16x4*)&Xh[tt][32 + c4] = *(const bf16x4*)(childrenH + o1);
        *(bf16x4*)&Xl[tt][32 + c4] = *(const bf16x4*)(childrenL + o1);
    }
    __syncthreads();

    #pragma unroll 1
    for (int it = 1; it <= 16; ++it) {
        const bool fin = (it == 16);
        if (fin) {   // swap to cb weights (last iteration)
            #pragma unroll
            for (int nt = 0; nt < 2; ++nt)
                #pragma unroll
                for (int kc = 0; kc < 2; ++kc) {
                    const int n = w * 32 + nt * 16 + lm;
                    W1r[nt][kc][0] = *(const bf16x8*)(cbW1Th + n * 64 + kc * 32 + kb * 8);
                    W1r[nt][kc][1] = *(const bf16x8*)(cbW1Tl + n * 64 + kc * 32 + kb * 8);
                }
            const int n2 = (w & 1) * 16 + lm;
            #pragma unroll
            for (int kc = 0; kc < 4; ++kc) {
                W2r[kc][0] = *(const bf16x8*)(cbW2Th + n2 * 128 + kc * 32 + kb * 8);
                W2r[kc][1] = *(const bf16x8*)(cbW2Tl + n2 * 128 + kc * 32 + kb * 8);
            }
        }
        const float* __restrict__ b1c = fin ? b1b : b1a;
        const float* __restrict__ b2c = fin ? b2b : b2a;

        // prefetch next child (or node_tmp before the combine step)
        bf16x4 pfh, pfl;
        const int pfmode = (it < 15) ? 1 : (it == 15 ? 2 : 0);
        if (pfmode == 1) {
            const size_t o = ((base + tt) * 16 + (it + 1)) * 32 + c4;
            pfh = *(const bf16x4*)(childrenH + o);
            pfl = *(const bf16x4*)(childrenL + o);
        } else if (pfmode == 2) {
            const size_t o = (base + tt) * 32 + c4;
            pfh = *(const bf16x4*)(node_tmpH + o);
            pfl = *(const bf16x4*)(node_tmpL + o);
        }

        // ---- layer 1: A=W1 (cols), B=X (trees); split chains (depth 3) ----
        bf16x8 xh[2][2], xl[2][2];
        #pragma unroll
        for (int tn = 0; tn < 2; ++tn)
            #pragma unroll
            for (int kc = 0; kc < 2; ++kc) {
                xh[tn][kc] = *(const bf16x8*)&Xh[tn * 16 + lm][kc * 32 + kb * 8];
                xl[tn][kc] = *(const bf16x8*)&Xl[tn * 16 + lm][kc * 32 + kb * 8];
            }
        f32x4 a1[2][2];
        #pragma unroll
        for (int tn = 0; tn < 2; ++tn)
            #pragma unroll
            for (int nt = 0; nt < 2; ++nt) {
                f32x4 c0 = (f32x4){0.f, 0.f, 0.f, 0.f};
                f32x4 c1 = (f32x4){0.f, 0.f, 0.f, 0.f};
                c0 = __builtin_amdgcn_mfma_f32_16x16x32_bf16(W1r[nt][0][0], xh[tn][0], c0, 0, 0, 0);
                c1 = __builtin_amdgcn_mfma_f32_16x16x32_bf16(W1r[nt][1][0], xh[tn][1], c1, 0, 0, 0);
                c0 = __builtin_amdgcn_mfma_f32_16x16x32_bf16(W1r[nt][0][0], xl[tn][0], c0, 0, 0, 0);
                c1 = __builtin_amdgcn_mfma_f32_16x16x32_bf16(W1r[nt][1][0], xl[tn][1], c1, 0, 0, 0);
                c0 = __builtin_amdgcn_mfma_f32_16x16x32_bf16(W1r[nt][0][1], xh[tn][0], c0, 0, 0, 0);
                c1 = __builtin_amdgcn_mfma_f32_16x16x32_bf16(W1r[nt][1][1], xh[tn][1], c1, 0, 0, 0);
                a1[tn][nt] = c0 + c1;
            }
        // D: col = tree-in-tile, row = W1-col -> packed store (H hi only)
        #pragma unroll
        for (int tn = 0; tn < 2; ++tn)
            #pragma unroll
            for (int nt = 0; nt < 2; ++nt) {
                const int wcol = w * 32 + nt * 16 + 4 * kb;
                bf16x4 ph;
                #pragma unroll
                for (int rg = 0; rg < 4; ++rg) {
                    float v = a1[tn][nt][rg] + b1c[wcol + rg];
                    v = v > 0.f ? v : 0.f;
                    ph[rg] = (__bf16)v;
                }
                *(bf16x4*)&Hh[tn * 16 + lm][wcol] = ph;
            }
        __syncthreads();

        // ---- layer 2: A=W2 (hi+lo), B=H (hi only); split chains (depth 4) ----
        const int mt = w >> 1, jn = w & 1;
        f32x4 a2a = (f32x4){0.f, 0.f, 0.f, 0.f};
        f32x4 a2b = (f32x4){0.f, 0.f, 0.f, 0.f};
        #pragma unroll
        for (int kc = 0; kc < 2; ++kc) {
            const bf16x8 hhA = *(const bf16x8*)&Hh[mt * 16 + lm][kc * 32 + kb * 8];
            const bf16x8 hhB = *(const bf16x8*)&Hh[mt * 16 + lm][(kc + 2) * 32 + kb * 8];
            a2a = __builtin_amdgcn_mfma_f32_16x16x32_bf16(W2r[kc][0], hhA, a2a, 0, 0, 0);
            a2b = __builtin_amdgcn_mfma_f32_16x16x32_bf16(W2r[kc + 2][0], hhB, a2b, 0, 0, 0);
            a2a = __builtin_amdgcn_mfma_f32_16x16x32_bf16(W2r[kc][1], hhA, a2a, 0, 0, 0);
            a2b = __builtin_amdgcn_mfma_f32_16x16x32_bf16(W2r[kc + 2][1], hhB, a2b, 0, 0, 0);
        }
        const f32x4 a2 = a2a + a2b;

        if (!fin) {
            // new carry: tree = mt*16+lm, feats jn*16+4kb..+3 (packed)
            const int cb_ = (it == 15) ? 32 : 0;
            const int ocol = jn * 16 + 4 * kb;
            bf16x4 ph, pl;
            #pragma unroll
            for (int rg = 0; rg < 4; ++rg) {
                float v = a2[rg] + b2c[ocol + rg];
                v = v > 0.f ? v : 0.f;
                const __bf16 h = (__bf16)v;
                ph[rg] = h;
                pl[rg] = (__bf16)(v - (float)h);
            }
            *(bf16x4*)&Xh[mt * 16 + lm][cb_ + ocol] = ph;
            *(bf16x4*)&Xl[mt * 16 + lm][cb_ + ocol] = pl;
            if (pfmode) {
                const int dst = (pfmode == 2) ? 0 : 32;
                *(bf16x4*)&Xh[tt][dst + c4] = pfh;
                *(bf16x4*)&Xl[tt][dst + c4] = pfl;
            }
            __syncthreads();
        } else {
            // fused final linear: out = tree_sum . vfin + cfin
            const int ocol = jn * 16 + 4 * kb;
            float p = 0.f;
            #pragma unroll
            for (int rg = 0; rg < 4; ++rg) {
                float v = a2[rg] + b2c[ocol + rg];
                v = v > 0.f ? v : 0.f;
                p = fmaf(v, vfin[ocol + rg], p);
            }
            p += __shfl_xor(p, 16, 64);
            p += __shfl_xor(p, 32, 64);
            if (kb == 0) psum[jn][mt * 16 + lm] = p;
            __syncthreads();
            if (tid < 32) out[base + tid] = cfin_s + psum[0][tid] + psum[1][tid];
        }
    }
}

extern "C" void kernel_launch(void* const* d_in, const int* in_sizes, int n_in,
                              void* d_out, int out_size, void* d_ws, size_t ws_size,
                              hipStream_t stream) {
    const int*   trees      = (const int*)d_in[0];
    const float* lstm       = (const float*)d_in[1];
    const float* embedding  = (const float*)d_in[4];
    const float* leaf_end_W = (const float*)d_in[5];
    const float* leaf_end_b = (const float*)d_in[6];
    const float* lc_W1 = (const float*)d_in[7];
    const float* lc_b1 = (const float*)d_in[8];
    const float* lc_W2 = (const float*)d_in[9];
    const float* lc_b2 = (const float*)d_in[10];
    const float* cs_W1 = (const float*)d_in[11];
    const float* cs_b1 = (const float*)d_in[12];
    const float* cs_W2 = (const float*)d_in[13];
    const float* cs_b2 = (const float*)d_in[14];
    const float* nf_W1 = (const float*)d_in[15];
    const float* nf_b1 = (const float*)d_in[16];
    const float* nf_W2 = (const float*)d_in[17];
    const float* nf_b2 = (const float*)d_in[18];
    const float* cb_W1 = (const float*)d_in[19];
    const float* cb_b1 = (const float*)d_in[20];
    const float* cb_W2 = (const float*)d_in[21];
    const float* cb_b2 = (const float*)d_in[22];
    const float* ff_W1 = (const float*)d_in[23];
    const float* ff_b1 = (const float*)d_in[24];
    const float* ff_W2 = (const float*)d_in[25];
    const float* ff_b2 = (const float*)d_in[26];
    const float* ts_W  = (const float*)d_in[27];
    const float* ts_b  = (const float*)d_in[28];

    char* ws = (char*)d_ws;
    __bf16* childrenH = (__bf16*)ws;                             // 8 MiB
    __bf16* childrenL = (__bf16*)(ws + 8388608);                 // 8 MiB
    __bf16* node_tmpH = (__bf16*)(ws + 16777216);                // 0.5 MiB
    __bf16* node_tmpL = (__bf16*)(ws + 17301504);                // 0.5 MiB
    __bf16* lcW1T    = (__bf16*)(ws + 17825792);
    __bf16* nfW1T    = (__bf16*)(ws + 17948672);
    __bf16* lcW2T    = (__bf16*)(ws + 18071552);
    __bf16* nfW2T    = (__bf16*)(ws + 18079744);
    __bf16* emb_bf   = (__bf16*)(ws + 18087936);
    float*  endvec   = (float*)(ws + 18094336);
    __bf16* csW1Th   = (__bf16*)(ws + 18094464);
    __bf16* csW1Tl   = (__bf16*)(ws + 18110848);
    __bf16* cbW1Th   = (__bf16*)(ws + 18127232);
    __bf16* cbW1Tl   = (__bf16*)(ws + 18143616);
    __bf16* csW2Th   = (__bf16*)(ws + 18160000);
    __bf16* csW2Tl   = (__bf16*)(ws + 18168192);
    __bf16* cbW2Th   = (__bf16*)(ws + 18176384);
    __bf16* cbW2Tl   = (__bf16*)(ws + 18184576);
    float*  vfin     = (float*)(ws + 18192768);
    float*  cfin     = (float*)(ws + 18192896);
    float*  outp     = (float*)d_out;

    prep_kernel<<<dim3(621), dim3(256), 0, stream>>>(
        embedding, leaf_end_W, leaf_end_b, lc_W1, lc_W2, nf_W1, nf_W2,
        cs_W1, cs_W2, cb_W1, cb_W2, ff_W1, ff_b1, ff_W2, ff_b2, ts_W, ts_b,
        lcW1T, nfW1T, lcW2T, nfW2T, emb_bf, endvec,
        csW1Th, csW1Tl, cbW1Th, cbW1Tl, csW2Th, csW2Tl, cbW2Th, cbW2Tl,
        vfin, cfin);

    mlp1_mfma<<<dim3(2176), dim3(256), 0, stream>>>(
        trees, lstm, lcW1T, nfW1T, lcW2T, nfW2T, emb_bf, endvec,
        lc_b1, lc_b2, nf_b1, nf_b2, childrenH, childrenL, node_tmpH, node_tmpL);

    scan_mfma<<<dim3(256), dim3(256), 0, stream>>>(
        childrenH, childrenL, node_tmpH, node_tmpL,
        csW1Th, csW1Tl, csW2Th, csW2Tl, cbW1Th, cbW1Tl, cbW2Th, cbW2Tl,
        cs_b1, cs_b2, cb_b1, cb_b2, vfin, cfin, outp);
}

// Round 12
// 121.372 us; speedup vs baseline: 1.1691x; 1.0412x over previous
//
#include <hip/hip_runtime.h>
#include <cstddef>

// B=8192 trees, 16 leaves + 1 root. FEAT=480 (14 tok x 16 emb + 256 lstm).
// prep_kernel: read-coalesced bf16 transposes (lc/nf W1/W2, hi/lo cs/cb), emb,
//              endvec, vfin/cfin collapse of the final linear chain.
// mlp1_mfma:   R6-exact + token indices hoisted to registers pre-barrier:
//              64 rows/block, 2 row-tiles x 1 col-half per wave, barrier-free
//              K-loop, packed bf16x4 stores, padded emb LDS.
// scan_mfma:   R6-exact: 32 trees/block x 256 blocks x 4 waves, hi/lo split
//              MFMA, weights register-resident, fused final dot.

typedef __bf16 bf16x8 __attribute__((ext_vector_type(8)));
typedef __bf16 bf16x4 __attribute__((ext_vector_type(4)));
typedef float  f32x4  __attribute__((ext_vector_type(4)));

__global__ __launch_bounds__(256) void prep_kernel(
    const float* __restrict__ embedding,
    const float* __restrict__ leaf_end_W, const float* __restrict__ leaf_end_b,
    const float* __restrict__ lc_W1, const float* __restrict__ lc_W2,
    const float* __restrict__ nf_W1, const float* __restrict__ nf_W2,
    const float* __restrict__ cs_W1, const float* __restrict__ cs_W2,
    const float* __restrict__ cb_W1, const float* __restrict__ cb_W2,
    const float* __restrict__ ff_W1, const float* __restrict__ ff_b1,
    const float* __restrict__ ff_W2, const float* __restrict__ ff_b2,
    const float* __restrict__ ts_W, const float* __restrict__ ts_b,
    __bf16* __restrict__ lcW1T, __bf16* __restrict__ nfW1T,
    __bf16* __restrict__ lcW2T, __bf16* __restrict__ nfW2T,
    __bf16* __restrict__ emb_bf, float* __restrict__ endvec,
    __bf16* __restrict__ csW1Th, __bf16* __restrict__ csW1Tl,
    __bf16* __restrict__ cbW1Th, __bf16* __restrict__ cbW1Tl,
    __bf16* __restrict__ csW2Th, __bf16* __restrict__ csW2Tl,
    __bf16* __restrict__ cbW2Th, __bf16* __restrict__ cbW2Tl,
    float* __restrict__ vfin, float* __restrict__ cfin)
{
    const int id = blockIdx.x * 256 + threadIdx.x;
    if (id < 61440) {                        // lc_W1[k][n] read coalesced
        const int k = id >> 7, n = id & 127;
        lcW1T[n * 480 + k] = (__bf16)lc_W1[id];
    } else if (id < 122880) {
        const int e = id - 61440;
        const int k = e >> 7, n = e & 127;
        nfW1T[n * 480 + k] = (__bf16)nf_W1[e];
    } else if (id < 126976) {                // lc_W2[k][n] read coalesced
        const int e = id - 122880;
        const int k = e >> 5, n = e & 31;
        lcW2T[n * 128 + k] = (__bf16)lc_W2[e];
    } else if (id < 131072) {
        const int e = id - 126976;
        const int k = e >> 5, n = e & 31;
        nfW2T[n * 128 + k] = (__bf16)nf_W2[e];
    } else if (id < 134272) {
        emb_bf[id - 131072] = (__bf16)embedding[id - 131072];
    } else if (id < 134304) {                // endvec = emb[1] @ leaf_end_W + b
        const int c = id - 134272;
        float a = leaf_end_b[c];
        #pragma unroll
        for (int d = 0; d < 16; ++d) a = fmaf(embedding[16 + d], leaf_end_W[d * 32 + c], a);
        endvec[c] = a;
    } else if (id < 142496) {                // cs_W1 hi/lo  [64][128] -> T[128][64]
        const int e = id - 134304;
        const int k = e >> 7, n = e & 127;
        const float v = cs_W1[e];
        const __bf16 h = (__bf16)v;
        csW1Th[n * 64 + k] = h; csW1Tl[n * 64 + k] = (__bf16)(v - (float)h);
    } else if (id < 150688) {                // cb_W1 hi/lo
        const int e = id - 142496;
        const int k = e >> 7, n = e & 127;
        const float v = cb_W1[e];
        const __bf16 h = (__bf16)v;
        cbW1Th[n * 64 + k] = h; cbW1Tl[n * 64 + k] = (__bf16)(v - (float)h);
    } else if (id < 154784) {                // cs_W2 hi/lo  [128][32] -> T[32][128]
        const int e = id - 150688;
        const int k = e >> 5, n = e & 31;
        const float v = cs_W2[e];
        const __bf16 h = (__bf16)v;
        csW2Th[n * 128 + k] = h; csW2Tl[n * 128 + k] = (__bf16)(v - (float)h);
    } else if (id < 158880) {                // cb_W2 hi/lo
        const int e = id - 154784;
        const int k = e >> 5, n = e & 31;
        const float v = cb_W2[e];
        const __bf16 h = (__bf16)v;
        cbW2Th[n * 128 + k] = h; cbW2Tl[n * 128 + k] = (__bf16)(v - (float)h);
    } else if (id < 158912) {                // vfin[c] = ff_W1[c] . (ff_W2 @ ts_W)
        const int c = id - 158880;
        float w2t[32];
        #pragma unroll
        for (int k = 0; k < 32; ++k) {
            float a = 0.f;
            for (int j = 0; j < 32; ++j) a = fmaf(ff_W2[k * 32 + j], ts_W[j], a);
            w2t[k] = a;
        }
        float a = 0.f;
        #pragma unroll
        for (int k = 0; k < 32; ++k) a = fmaf(ff_W1[c * 32 + k], w2t[k], a);
        vfin[c] = a;
    } else if (id == 158912) {
        float a = ts_b[0];
        for (int j = 0; j < 32; ++j) a = fmaf(ff_b2[j], ts_W[j], a);
        for (int k = 0; k < 32; ++k) {
            float w2t = 0.f;
            for (int j = 0; j < 32; ++j) w2t = fmaf(ff_W2[k * 32 + j], ts_W[j], w2t);
            a = fmaf(ff_b1[k], w2t, a);
        }
        cfin[0] = a;
    }
}

// 64 rows/block: leaf blocks 0..2047 (131072 leaf rows), node blocks 2048..2175.
// Swapped operands: A = weights (m = out-col), B = gathered rows (n = row).
__global__ __launch_bounds__(256, 4) void mlp1_mfma(
    const int* __restrict__ trees,
    const float* __restrict__ lstm,
    const __bf16* __restrict__ lcW1T, const __bf16* __restrict__ nfW1T,
    const __bf16* __restrict__ lcW2T, const __bf16* __restrict__ nfW2T,
    const __bf16* __restrict__ emb_bf, const float* __restrict__ endvec,
    const float* __restrict__ lc_b1, const float* __restrict__ lc_b2,
    const float* __restrict__ nf_b1, const float* __restrict__ nf_b2,
    __bf16* __restrict__ childrenH, __bf16* __restrict__ childrenL,
    __bf16* __restrict__ node_tmpH, __bf16* __restrict__ node_tmpL)
{
    __shared__ __align__(16) __bf16 emb_s[200 * 24];   // padded stride 24 (48B)
    __shared__ __align__(16) __bf16 Hs[64][136];
    __shared__ float b1s[128], b2s[32], evs[32];
    __shared__ int   endf[64];

    const int tid = threadIdx.x;
    const int blk = blockIdx.x;
    const bool leaf = (blk < 2048);

    const __bf16* __restrict__ W1T = leaf ? lcW1T : nfW1T;
    const __bf16* __restrict__ W2T = leaf ? lcW2T : nfW2T;
    const float*  __restrict__ b1p = leaf ? lc_b1 : nf_b1;
    const float*  __restrict__ b2p = leaf ? lc_b2 : nf_b2;

    const int l  = tid & 63;
    const int w  = tid >> 6;        // wave 0..3
    const int lm = l & 15;
    const int kb = l >> 4;          // k sub-block 0..3
    const int wm = w >> 1;          // row half (rows wm*32..+31)
    const int wn = w & 1;           // W1-col half (cols wn*64..+63)

    // gather pointers + hoisted token indices for this wave's 2 row-tiles
    const float* lb[2];
    int tk[2][7];
    #pragma unroll
    for (int i = 0; i < 2; ++i) {
        const int r = wm * 32 + i * 16 + lm;
        int b, trow;
        if (leaf) { const int R = blk * 64 + r; b = R >> 4; trow = 1 + (R & 15); }
        else      { b = (blk - 2048) * 64 + r; trow = 0; }
        const int* t = trees + (b * 17 + trow) * 17;
        lb[i] = lstm + ((size_t)b * 64 + (size_t)t[16]) * 256;
        #pragma unroll
        for (int c = 0; c < 7; ++c) tk[i][c] = t[2 + 2 * c + (kb >> 1)];
    }

    // staging (padded embedding rows)
    for (int i = tid; i < 3200; i += 256) {
        const int row = i >> 4, col = i & 15;
        emb_s[row * 24 + col] = emb_bf[i];
    }
    if (tid < 128) b1s[tid] = b1p[tid];
    if (tid < 32)  { b2s[tid] = b2p[tid]; evs[tid] = leaf ? endvec[tid] : 0.f; }
    if (tid < 64) {
        if (leaf) {
            const int R = blk * 64 + tid;
            const int b = R >> 4, trow = 1 + (R & 15);
            endf[tid] = (trees[(b * 17 + trow) * 17 + 2] == 1);
        } else endf[tid] = 0;
    }

    f32x4 acc[2][4];
    #pragma unroll
    for (int i = 0; i < 2; ++i)
        #pragma unroll
        for (int j = 0; j < 4; ++j) acc[i][j] = (f32x4){0.f, 0.f, 0.f, 0.f};

    __syncthreads();

    // layer 1: 480 -> 128 in 15 K-chunks of 32. A = W1 cols, B = rows.
    #pragma unroll
    for (int c = 0; c < 15; ++c) {
        bf16x8 wfr[4];
        #pragma unroll
        for (int ct = 0; ct < 4; ++ct) {
            const int n = wn * 64 + ct * 16 + lm;
            wfr[ct] = *(const bf16x8*)(W1T + n * 480 + c * 32 + kb * 8);
        }
        bf16x8 bfr[2];
        if (c < 7) {
            #pragma unroll
            for (int i = 0; i < 2; ++i) {
                bfr[i] = *(const bf16x8*)(emb_s + tk[i][c] * 24 + (kb & 1) * 8);
            }
        } else {
            #pragma unroll
            for (int i = 0; i < 2; ++i) {
                const float* p = lb[i] + (c - 7) * 32 + kb * 8;
                const float4 u = *(const float4*)p;
                const float4 v = *(const float4*)(p + 4);
                bf16x8 t;
                t[0] = (__bf16)u.x; t[1] = (__bf16)u.y; t[2] = (__bf16)u.z; t[3] = (__bf16)u.w;
                t[4] = (__bf16)v.x; t[5] = (__bf16)v.y; t[6] = (__bf16)v.z; t[7] = (__bf16)v.w;
                bfr[i] = t;
            }
        }
        #pragma unroll
        for (int i = 0; i < 2; ++i)
            #pragma unroll
            for (int ct = 0; ct < 4; ++ct)
                acc[i][ct] = __builtin_amdgcn_mfma_f32_16x16x32_bf16(wfr[ct], bfr[i], acc[i][ct], 0, 0, 0);
    }

    // D: col(lane&15) = row-in-tile, row(4*kb+rg) = W1-col -> packed 4-col store
    #pragma unroll
    for (int i = 0; i < 2; ++i)
        #pragma unroll
        for (int ct = 0; ct < 4; ++ct) {
            const int wcol = wn * 64 + ct * 16 + 4 * kb;
            bf16x4 pk;
            #pragma unroll
            for (int rg = 0; rg < 4; ++rg) {
                float v = acc[i][ct][rg] + b1s[wcol + rg];
                v = v > 0.f ? v : 0.f;
                pk[rg] = (__bf16)v;
            }
            *(bf16x4*)&Hs[wm * 32 + i * 16 + lm][wcol] = pk;
        }
    __syncthreads();

    // layer 2: 64x32. wave w: outcol tile jn=w&1, row-tiles {2*(w>>1)+i}.
    const int jn = w & 1, rb2 = 2 * (w >> 1);
    f32x4 acc2[2];
    acc2[0] = (f32x4){0.f, 0.f, 0.f, 0.f};
    acc2[1] = (f32x4){0.f, 0.f, 0.f, 0.f};

    #pragma unroll
    for (int kc = 0; kc < 4; ++kc) {
        const bf16x8 wf = *(const bf16x8*)(W2T + (jn * 16 + lm) * 128 + kc * 32 + kb * 8);
        #pragma unroll
        for (int i = 0; i < 2; ++i) {
            const bf16x8 hf = *(const bf16x8*)(&Hs[(rb2 + i) * 16 + lm][kc * 32 + kb * 8]);
            acc2[i] = __builtin_amdgcn_mfma_f32_16x16x32_bf16(wf, hf, acc2[i], 0, 0, 0);
        }
    }

    #pragma unroll
    for (int i = 0; i < 2; ++i) {
        const int orow = (rb2 + i) * 16 + lm;     // row within block
        const int ocol = jn * 16 + 4 * kb;        // +rg
        const bool isend = leaf && endf[orow];
        bf16x4 ph, pl;
        #pragma unroll
        for (int rg = 0; rg < 4; ++rg) {
            float v = acc2[i][rg] + b2s[ocol + rg];
            v = v > 0.f ? v : 0.f;
            if (isend) v = evs[ocol + rg];
            const __bf16 h = (__bf16)v;
            ph[rg] = h;
            pl[rg] = (__bf16)(v - (float)h);
        }
        if (leaf) {
            const size_t R = (size_t)blk * 64 + orow;
            *(bf16x4*)&childrenH[R * 32 + ocol] = ph;
            *(bf16x4*)&childrenL[R * 32 + ocol] = pl;
        } else {
            const size_t R = (size_t)(blk - 2048) * 64 + orow;
            *(bf16x4*)&node_tmpH[R * 32 + ocol] = ph;
            *(bf16x4*)&node_tmpL[R * 32 + ocol] = pl;
        }
    }
}

// 32 trees/block, 256 blocks, 4 waves (R6-verbatim). Swapped operands; packed LDS IO.
__global__ __launch_bounds__(256) void scan_mfma(
    const __bf16* __restrict__ childrenH, const __bf16* __restrict__ childrenL,
    const __bf16* __restrict__ node_tmpH, const __bf16* __restrict__ node_tmpL,
    const __bf16* __restrict__ csW1Th, const __bf16* __restrict__ csW1Tl,
    const __bf16* __restrict__ csW2Th, const __bf16* __restrict__ csW2Tl,
    const __bf16* __restrict__ cbW1Th, const __bf16* __restrict__ cbW1Tl,
    const __bf16* __restrict__ cbW2Th, const __bf16* __restrict__ cbW2Tl,
    const float* __restrict__ cs_b1, const float* __restrict__ cs_b2,
    const float* __restrict__ cb_b1, const float* __restrict__ cb_b2,
    const float* __restrict__ vfin_g, const float* __restrict__ cfin_g,
    float* __restrict__ out)
{
    __shared__ __align__(16) __bf16 Xh[32][72], Xl[32][72];
    __shared__ __align__(16) __bf16 Hh[32][136], Hl[32][136];
    __shared__ float b1a[128], b1b[128], b2a[32], b2b[32], vfin[32];
    __shared__ float psum[2][32];
    __shared__ float cfin_s;

    const int tid = threadIdx.x;
    const int l = tid & 63, w = tid >> 6;      // 4 waves
    const int lm = l & 15, kb = l >> 4;

    if (tid < 128)      { b1a[tid] = cs_b1[tid]; b1b[tid] = cb_b1[tid]; }
    else if (tid < 160) { b2a[tid - 128] = cs_b2[tid - 128]; b2b[tid - 128] = cb_b2[tid - 128]; }
    else if (tid < 192) { vfin[tid - 160] = vfin_g[tid - 160]; }
    else if (tid == 192) cfin_s = cfin_g[0];

    // layer1 weights (A-frags): wave w owns cols [w*32, +32): 2 tiles x 2 K-chunks
    bf16x8 W1r[2][2][2];   // [nt][kc][hi/lo]
    #pragma unroll
    for (int nt = 0; nt < 2; ++nt)
        #pragma unroll
        for (int kc = 0; kc < 2; ++kc) {
            const int n = w * 32 + nt * 16 + lm;
            W1r[nt][kc][0] = *(const bf16x8*)(csW1Th + n * 64 + kc * 32 + kb * 8);
            W1r[nt][kc][1] = *(const bf16x8*)(csW1Tl + n * 64 + kc * 32 + kb * 8);
        }
    // layer2 weights: wave w owns outcols (w&1)*16.. ; 4 K-chunks
    bf16x8 W2r[4][2];
    {
        const int n2 = (w & 1) * 16 + lm;
        #pragma unroll
        for (int kc = 0; kc < 4; ++kc) {
            W2r[kc][0] = *(const bf16x8*)(csW2Th + n2 * 128 + kc * 32 + kb * 8);
            W2r[kc][1] = *(const bf16x8*)(csW2Tl + n2 * 128 + kc * 32 + kb * 8);
        }
    }

    const size_t base = (size_t)blockIdx.x * 32;
    const int tt = tid >> 3, c4 = (tid & 7) * 4;    // staging: tree tt, cols c4..

    {
        const size_t o0 = ((base + tt) * 16 + 0) * 32 + c4;
        const size_t o1 = ((base + tt) * 16 + 1) * 32 + c4;
        *(bf16x4*)&Xh[tt][c4]      = *(const bf16x4*)(childrenH + o0);
        *(bf16x4*)&Xl[tt][c4]      = *(const bf16x4*)(childrenL + o0);
        *(bf16x4*)&Xh[tt][32 + c4] = *(const bf16x4*)(childrenH + o1);
        *(bf16x4*)&Xl[tt][32 + c4] = *(const bf16x4*)(childrenL + o1);
    }
    __syncthreads();

    #pragma unroll 1
    for (int it = 1; it <= 16; ++it) {
        const bool fin = (it == 16);
        if (fin) {   // swap to cb weights (last iteration)
            #pragma unroll
            for (int nt = 0; nt < 2; ++nt)
                #pragma unroll
                for (int kc = 0; kc < 2; ++kc) {
                    const int n = w * 32 + nt * 16 + lm;
                    W1r[nt][kc][0] = *(const bf16x8*)(cbW1Th + n * 64 + kc * 32 + kb * 8);
                    W1r[nt][kc][1] = *(const bf16x8*)(cbW1Tl + n * 64 + kc * 32 + kb * 8);
                }
            const int n2 = (w & 1) * 16 + lm;
            #pragma unroll
            for (int kc = 0; kc < 4; ++kc) {
                W2r[kc][0] = *(const bf16x8*)(cbW2Th + n2 * 128 + kc * 32 + kb * 8);
                W2r[kc][1] = *(const bf16x8*)(cbW2Tl + n2 * 128 + kc * 32 + kb * 8);
            }
        }
        const float* __restrict__ b1c = fin ? b1b : b1a;
        const float* __restrict__ b2c = fin ? b2b : b2a;

        // prefetch next child (or node_tmp before the combine step)
        bf16x4 pfh, pfl;
        const int pfmode = (it < 15) ? 1 : (it == 15 ? 2 : 0);
        if (pfmode == 1) {
            const size_t o = ((base + tt) * 16 + (it + 1)) * 32 + c4;
            pfh = *(const bf16x4*)(childrenH + o);
            pfl = *(const bf16x4*)(childrenL + o);
        } else if (pfmode == 2) {
            const size_t o = (base + tt) * 32 + c4;
            pfh = *(const bf16x4*)(node_tmpH + o);
            pfl = *(const bf16x4*)(node_tmpL + o);
        }

        // ---- layer 1: A=W1 (cols), B=X (trees) ----
        bf16x8 xh[2][2], xl[2][2];
        #pragma unroll
        for (int tn = 0; tn < 2; ++tn)
            #pragma unroll
            for (int kc = 0; kc < 2; ++kc) {
                xh[tn][kc] = *(const bf16x8*)&Xh[tn * 16 + lm][kc * 32 + kb * 8];
                xl[tn][kc] = *(const bf16x8*)&Xl[tn * 16 + lm][kc * 32 + kb * 8];
            }
        f32x4 a1[2][2];
        #pragma unroll
        for (int tn = 0; tn < 2; ++tn)
            #pragma unroll
            for (int nt = 0; nt < 2; ++nt) {
                a1[tn][nt] = (f32x4){0.f, 0.f, 0.f, 0.f};
                #pragma unroll
                for (int kc = 0; kc < 2; ++kc) {
                    a1[tn][nt] = __builtin_amdgcn_mfma_f32_16x16x32_bf16(W1r[nt][kc][0], xh[tn][kc], a1[tn][nt], 0, 0, 0);
                    a1[tn][nt] = __builtin_amdgcn_mfma_f32_16x16x32_bf16(W1r[nt][kc][0], xl[tn][kc], a1[tn][nt], 0, 0, 0);
                    a1[tn][nt] = __builtin_amdgcn_mfma_f32_16x16x32_bf16(W1r[nt][kc][1], xh[tn][kc], a1[tn][nt], 0, 0, 0);
                }
            }
        // D: col = tree-in-tile, row = W1-col -> packed stores
        #pragma unroll
        for (int tn = 0; tn < 2; ++tn)
            #pragma unroll
            for (int nt = 0; nt < 2; ++nt) {
                const int wcol = w * 32 + nt * 16 + 4 * kb;
                bf16x4 ph, pl;
                #pragma unroll
                for (int rg = 0; rg < 4; ++rg) {
                    float v = a1[tn][nt][rg] + b1c[wcol + rg];
                    v = v > 0.f ? v : 0.f;
                    const __bf16 h = (__bf16)v;
                    ph[rg] = h;
                    pl[rg] = (__bf16)(v - (float)h);
                }
                *(bf16x4*)&Hh[tn * 16 + lm][wcol] = ph;
                *(bf16x4*)&Hl[tn * 16 + lm][wcol] = pl;
            }
        __syncthreads();

        // ---- layer 2: A=W2, B=H ----
        const int mt = w >> 1, jn = w & 1;
        f32x4 a2 = (f32x4){0.f, 0.f, 0.f, 0.f};
        #pragma unroll
        for (int kc = 0; kc < 4; ++kc) {
            const bf16x8 hh = *(const bf16x8*)&Hh[mt * 16 + lm][kc * 32 + kb * 8];
            const bf16x8 hl = *(const bf16x8*)&Hl[mt * 16 + lm][kc * 32 + kb * 8];
            a2 = __builtin_amdgcn_mfma_f32_16x16x32_bf16(W2r[kc][0], hh, a2, 0, 0, 0);
            a2 = __builtin_amdgcn_mfma_f32_16x16x32_bf16(W2r[kc][0], hl, a2, 0, 0, 0);
            a2 = __builtin_amdgcn_mfma_f32_16x16x32_bf16(W2r[kc][1], hh, a2, 0, 0, 0);
        }

        if (!fin) {
            // new carry: tree = mt*16+lm, feats jn*16+4kb..+3 (packed)
            const int cb_ = (it == 15) ? 32 : 0;
            const int ocol = jn * 16 + 4 * kb;
            bf16x4 ph, pl;
            #pragma unroll
            for (int rg = 0; rg < 4; ++rg) {
                float v = a2[rg] + b2c[ocol + rg];
                v = v > 0.f ? v : 0.f;
                const __bf16 h = (__bf16)v;
                ph[rg] = h;
                pl[rg] = (__bf16)(v - (float)h);
            }
            *(bf16x4*)&Xh[mt * 16 + lm][cb_ + ocol] = ph;
            *(bf16x4*)&Xl[mt * 16 + lm][cb_ + ocol] = pl;
            if (pfmode) {
                const int dst = (pfmode == 2) ? 0 : 32;
                *(bf16x4*)&Xh[tt][dst + c4] = pfh;
                *(bf16x4*)&Xl[tt][dst + c4] = pfl;
            }
            __syncthreads();
        } else {
            // fused final linear: out = tree_sum . vfin + cfin
            const int ocol = jn * 16 + 4 * kb;
            float p = 0.f;
            #pragma unroll
            for (int rg = 0; rg < 4; ++rg) {
                float v = a2[rg] + b2c[ocol + rg];
                v = v > 0.f ? v : 0.f;
                p = fmaf(v, vfin[ocol + rg], p);
            }
            p += __shfl_xor(p, 16, 64);
            p += __shfl_xor(p, 32, 64);
            if (kb == 0) psum[jn][mt * 16 + lm] = p;
            __syncthreads();
            if (tid < 32) out[base + tid] = cfin_s + psum[0][tid] + psum[1][tid];
        }
    }
}

extern "C" void kernel_launch(void* const* d_in, const int* in_sizes, int n_in,
                              void* d_out, int out_size, void* d_ws, size_t ws_size,
                              hipStream_t stream) {
    const int*   trees      = (const int*)d_in[0];
    const float* lstm       = (const float*)d_in[1];
    const float* embedding  = (const float*)d_in[4];
    const float* leaf_end_W = (const float*)d_in[5];
    const float* leaf_end_b = (const float*)d_in[6];
    const float* lc_W1 = (const float*)d_in[7];
    const float* lc_b1 = (const float*)d_in[8];
    const float* lc_W2 = (const float*)d_in[9];
    const float* lc_b2 = (const float*)d_in[10];
    const float* cs_W1 = (const float*)d_in[11];
    const float* cs_b1 = (const float*)d_in[12];
    const float* cs_W2 = (const float*)d_in[13];
    const float* cs_b2 = (const float*)d_in[14];
    const float* nf_W1 = (const float*)d_in[15];
    const float* nf_b1 = (const float*)d_in[16];
    const float* nf_W2 = (const float*)d_in[17];
    const float* nf_b2 = (const float*)d_in[18];
    const float* cb_W1 = (const float*)d_in[19];
    const float* cb_b1 = (const float*)d_in[20];
    const float* cb_W2 = (const float*)d_in[21];
    const float* cb_b2 = (const float*)d_in[22];
    const float* ff_W1 = (const float*)d_in[23];
    const float* ff_b1 = (const float*)d_in[24];
    const float* ff_W2 = (const float*)d_in[25];
    const float* ff_b2 = (const float*)d_in[26];
    const float* ts_W  = (const float*)d_in[27];
    const float* ts_b  = (const float*)d_in[28];

    char* ws = (char*)d_ws;
    __bf16* childrenH = (__bf16*)ws;                             // 8 MiB
    __bf16* childrenL = (__bf16*)(ws + 8388608);                 // 8 MiB
    __bf16* node_tmpH = (__bf16*)(ws + 16777216);                // 0.5 MiB
    __bf16* node_tmpL = (__bf16*)(ws + 17301504);                // 0.5 MiB
    __bf16* lcW1T    = (__bf16*)(ws + 17825792);
    __bf16* nfW1T    = (__bf16*)(ws + 17948672);
    __bf16* lcW2T    = (__bf16*)(ws + 18071552);
    __bf16* nfW2T    = (__bf16*)(ws + 18079744);
    __bf16* emb_bf   = (__bf16*)(ws + 18087936);
    float*  endvec   = (float*)(ws + 18094336);
    __bf16* csW1Th   = (__bf16*)(ws + 18094464);
    __bf16* csW1Tl   = (__bf16*)(ws + 18110848);
    __bf16* cbW1Th   = (__bf16*)(ws + 18127232);
    __bf16* cbW1Tl   = (__bf16*)(ws + 18143616);
    __bf16* csW2Th   = (__bf16*)(ws + 18160000);
    __bf16* csW2Tl   = (__bf16*)(ws + 18168192);
    __bf16* cbW2Th   = (__bf16*)(ws + 18176384);
    __bf16* cbW2Tl   = (__bf16*)(ws + 18184576);
    float*  vfin     = (float*)(ws + 18192768);
    float*  cfin     = (float*)(ws + 18192896);
    float*  outp     = (float*)d_out;

    prep_kernel<<<dim3(621), dim3(256), 0, stream>>>(
        embedding, leaf_end_W, leaf_end_b, lc_W1, lc_W2, nf_W1, nf_W2,
        cs_W1, cs_W2, cb_W1, cb_W2, ff_W1, ff_b1, ff_W2, ff_b2, ts_W, ts_b,
        lcW1T, nfW1T, lcW2T, nfW2T, emb_bf, endvec,
        csW1Th, csW1Tl, cbW1Th, cbW1Tl, csW2Th, csW2Tl, cbW2Th, cbW2Tl,
        vfin, cfin);

    mlp1_mfma<<<dim3(2176), dim3(256), 0, stream>>>(
        trees, lstm, lcW1T, nfW1T, lcW2T, nfW2T, emb_bf, endvec,
        lc_b1, lc_b2, nf_b1, nf_b2, childrenH, childrenL, node_tmpH, node_tmpL);

    scan_mfma<<<dim3(256), dim3(256), 0, stream>>>(
        childrenH, childrenL, node_tmpH, node_tmpL,
        csW1Th, csW1Tl, csW2Th, csW2Tl, cbW1Th, cbW1Tl, cbW2Th, cbW2Tl,
        cs_b1, cs_b2, cb_b1, cb_b2, vfin, cfin, outp);
}